// Round 1
// baseline (327.390 us; speedup 1.0000x reference)
//
#include <hip/hip_runtime.h>
#include <stdint.h>

typedef unsigned short u16;
typedef unsigned int   u32;
typedef __attribute__((ext_vector_type(8))) short short8;   // 8 x bf16 fragment
typedef __attribute__((ext_vector_type(4))) float f32x4;    // MFMA accumulator

// ---------- helpers ----------
__device__ __forceinline__ u16 f2bf(float f) {          // RNE f32 -> bf16
  u32 u = __builtin_bit_cast(u32, f);
  u32 r = u + 0x7FFFu + ((u >> 16) & 1u);
  return (u16)(r >> 16);
}

// async global->LDS, 16B per lane (dest must be wave-uniform base + lane*16)
__device__ __forceinline__ void gload_lds16(const void* g, void* l) {
  __builtin_amdgcn_global_load_lds(
      (__attribute__((address_space(1))) void*)(uintptr_t)g,
      (__attribute__((address_space(3))) void*)(u32)(uintptr_t)l,
      16, 0, 0);
}

// ---------- elementwise f32 -> bf16 cast (8 elems/thread) ----------
__global__ void cast_kernel(const float* __restrict__ src, u16* __restrict__ dst, int n8) {
  int i = blockIdx.x * blockDim.x + threadIdx.x;
  if (i >= n8) return;
  const float4* s4 = (const float4*)src;
  float4 x = s4[2 * (size_t)i];
  float4 y = s4[2 * (size_t)i + 1];
  union { u16 u[8]; uint4 v; } r;
  r.u[0] = f2bf(x.x); r.u[1] = f2bf(x.y); r.u[2] = f2bf(x.z); r.u[3] = f2bf(x.w);
  r.u[4] = f2bf(y.x); r.u[5] = f2bf(y.y); r.u[6] = f2bf(y.z); r.u[7] = f2bf(y.w);
  *(uint4*)(dst + 8 * (size_t)i) = r.v;
}

// ---------- pack {q_seq, c_bits} per position ----------
__global__ void pack_kernel(const int* __restrict__ q_seq, const int* __restrict__ c_seq,
                            int2* __restrict__ meta, int n) {
  int i = blockIdx.x * blockDim.x + threadIdx.x;
  if (i >= n) return;
  u32 bits = 0;
#pragma unroll
  for (int j = 0; j < 32; ++j)
    bits |= (c_seq[(size_t)i * 32 + j] != 0) ? (1u << j) : 0u;
  meta[i] = make_int2(q_seq[i], (int)bits);
}

// ---------- GEMM: C[m][n] = sum_k A[m][k]*W[n][k] + bias[n] ----------
// A: bf16 [M][K]; W: bf16 [N][K] (row n = output col, K-contiguous = B^T layout)
// MODE 0: store bf16 to [b][h][s][64]   (b=row>>10, s=row&1023, h=col>>6, d=col&63)
// MODE 1: store bf16 to [b][h][64][1024] (V transposed)
// MODE 2: store f32 to [row][col] (row-major, N=512)
template <int MODE>
__global__ __launch_bounds__(256) void gemm_bt(const u16* __restrict__ A,
                                               const u16* __restrict__ W,
                                               const float* __restrict__ bias,
                                               void* __restrict__ outp,
                                               int M, int N, int K) {
  __shared__ __align__(16) u16 As[128 * 64];
  __shared__ __align__(16) u16 Bs[128 * 64];
  const int t    = threadIdx.x;
  const int lane = t & 63;
  const int wid  = t >> 6;
  const int g    = lane >> 4, l15 = lane & 15;
  const int wm   = wid >> 1, wn = wid & 1;           // 2x2 wave grid, 64x64 per wave
  const int nb   = N >> 7;
  const int mb   = blockIdx.x / nb, nbi = blockIdx.x % nb;
  const int m0   = mb << 7, n0 = nbi << 7;
  const int srow = t >> 3;                            // staging row within 32-row slab
  const int scol = (t & 7) << 3;                      // staging col (elements)

  f32x4 acc[4][4];
#pragma unroll
  for (int i = 0; i < 4; ++i)
#pragma unroll
    for (int j = 0; j < 4; ++j) acc[i][j] = f32x4{0.f, 0.f, 0.f, 0.f};

  for (int k0 = 0; k0 < K; k0 += 64) {
    __syncthreads();                                  // protect LDS from prev-iter reads
#pragma unroll
    for (int i = 0; i < 4; ++i) {
      const u16* sa = A + (size_t)(m0 + i * 32 + srow) * K + k0 + scol;
      const u16* sb = W + (size_t)(n0 + i * 32 + srow) * K + k0 + scol;
      gload_lds16(sa, As + i * 2048 + t * 8);
      gload_lds16(sb, Bs + i * 2048 + t * 8);
    }
    __syncthreads();                                  // drains vmcnt for global_load_lds
#pragma unroll
    for (int kk = 0; kk < 2; ++kk) {
      short8 a[4], b[4];
#pragma unroll
      for (int mi = 0; mi < 4; ++mi)
        a[mi] = *(const short8*)(As + (wm * 64 + mi * 16 + l15) * 64 + kk * 32 + g * 8);
#pragma unroll
      for (int ni = 0; ni < 4; ++ni)
        b[ni] = *(const short8*)(Bs + (wn * 64 + ni * 16 + l15) * 64 + kk * 32 + g * 8);
#pragma unroll
      for (int mi = 0; mi < 4; ++mi)
#pragma unroll
        for (int ni = 0; ni < 4; ++ni)
          acc[mi][ni] = __builtin_amdgcn_mfma_f32_16x16x32_bf16(a[mi], b[ni], acc[mi][ni], 0, 0, 0);
    }
  }

#pragma unroll
  for (int ni = 0; ni < 4; ++ni) {
    const int col = n0 + wn * 64 + ni * 16 + l15;
    const float bz = bias[col];
#pragma unroll
    for (int mi = 0; mi < 4; ++mi) {
#pragma unroll
      for (int r = 0; r < 4; ++r) {
        const int row = m0 + wm * 64 + mi * 16 + g * 4 + r;   // C/D: row=(lane>>4)*4+reg
        const float val = acc[mi][ni][r] + bz;
        if (MODE == 2) {
          ((float*)outp)[(size_t)row * N + col] = val;
        } else if (MODE == 0) {
          const size_t ad = ((size_t)(row >> 10) * 8 + (col >> 6)) * 65536
                          + (size_t)(row & 1023) * 64 + (col & 63);
          ((u16*)outp)[ad] = f2bf(val);
        } else {
          const size_t ad = ((size_t)(row >> 10) * 8 + (col >> 6)) * 65536
                          + (size_t)(col & 63) * 1024 + (row & 1023);
          ((u16*)outp)[ad] = f2bf(val);
        }
      }
    }
  }
}

// ---------- flash attention with QC mask + post-softmax adjustment ----------
// grid (S/32, H, B), 64 threads (1 wave). QBLK=KVBLK=32, D=64.
// qh,kh: [b][h][1024][64] bf16; vT: [b][h][64][1024] bf16; outc: [b*1024+s][512] bf16
__global__ __launch_bounds__(64) void attn_kernel(const u16* __restrict__ qh,
                                                  const u16* __restrict__ kh,
                                                  const u16* __restrict__ vT,
                                                  const int2* __restrict__ meta,
                                                  u16* __restrict__ outc) {
  const int qt = blockIdx.x, h = blockIdx.y, b = blockIdx.z;
  const int lane = threadIdx.x;
  const int g = lane >> 4, l15 = lane & 15;
  const int q0 = qt << 5;
  const size_t bh = (size_t)b * 8 + h;
  const u16* Q  = qh + bh * 65536;
  const u16* Kp = kh + bh * 65536;
  const u16* Vt = vT + bh * 65536;
  const int2* mb_ = meta + b * 1024;
  __shared__ __align__(16) u16 Pl[32 * 40];   // P tile, row stride 40 u16 (80B, 16B-aligned)

  // Q A-fragments: row = lane&15, k = 8*(lane>>4)+i (8 contiguous bf16)
  short8 qA[2][2];
#pragma unroll
  for (int f = 0; f < 2; ++f)
#pragma unroll
    for (int kk = 0; kk < 2; ++kk)
      qA[f][kk] = *(const short8*)(Q + (q0 + 16 * f + l15) * 64 + kk * 32 + g * 8);

  int rs[2][4]; u32 rb[2][4];
#pragma unroll
  for (int f = 0; f < 2; ++f)
#pragma unroll
    for (int r = 0; r < 4; ++r) {
      int2 mm = mb_[q0 + 16 * f + 4 * g + r];
      rs[f][r] = mm.x; rb[f][r] = (u32)mm.y;
    }

  float mrun[2][4], lrun[2][4];
  f32x4 o[2][4];
#pragma unroll
  for (int f = 0; f < 2; ++f) {
#pragma unroll
    for (int r = 0; r < 4; ++r) { mrun[f][r] = -1e30f; lrun[f][r] = 0.f; }
#pragma unroll
    for (int c2 = 0; c2 < 4; ++c2) o[f][c2] = f32x4{0.f, 0.f, 0.f, 0.f};
  }
  const f32x4 fzero = {0.f, 0.f, 0.f, 0.f};

  for (int tkv = 0; tkv <= qt; ++tkv) {
    const int k0 = tkv << 5;
    short8 kB[2][2], vB[4];
#pragma unroll
    for (int c = 0; c < 2; ++c)
#pragma unroll
      for (int kk = 0; kk < 2; ++kk)
        kB[c][kk] = *(const short8*)(Kp + (k0 + 16 * c + l15) * 64 + kk * 32 + g * 8);
#pragma unroll
    for (int c2 = 0; c2 < 4; ++c2)
      vB[c2] = *(const short8*)(Vt + (16 * c2 + l15) * 1024 + k0 + g * 8);

    int cs[2]; u32 cb[2];
#pragma unroll
    for (int c = 0; c < 2; ++c) {
      int2 mm = mb_[k0 + 16 * c + l15];
      cs[c] = mm.x; cb[c] = (u32)mm.y;
    }

    // S = Q K^T (32x32): 2x2 frags, K=64 -> 2 chained MFMAs each
    f32x4 sfr[2][2];
#pragma unroll
    for (int f = 0; f < 2; ++f)
#pragma unroll
      for (int c = 0; c < 2; ++c) {
        f32x4 tmp = __builtin_amdgcn_mfma_f32_16x16x32_bf16(qA[f][0], kB[c][0], fzero, 0, 0, 0);
        sfr[f][c] = __builtin_amdgcn_mfma_f32_16x16x32_bf16(qA[f][1], kB[c][1], tmp, 0, 0, 0);
      }

    // mask + adjustment weights
    float sv[2][2][4], aw[2][2][4];
#pragma unroll
    for (int f = 0; f < 2; ++f)
#pragma unroll
      for (int c = 0; c < 2; ++c)
#pragma unroll
        for (int r = 0; r < 4; ++r) {
          const int qi = q0 + 16 * f + 4 * g + r;
          const int kj = k0 + 16 * c + l15;
          int mi_ = 0;
          if (kj < qi)
            mi_ = 1 + (rs[f][r] == cs[c] ? 1 : 0) + (((rb[f][r] & cb[c]) != 0u) ? 1 : 0);
          aw[f][c][r] = mi_ ? 0.5f * (float)(1 << (mi_ - 1)) : 0.f;   // {_,0.5,1,2}
          sv[f][c][r] = mi_ ? sfr[f][c][r] * 0.125f : -1e30f;
        }

    // online softmax per row (reduce over 16-lane group = 16 cols; x2 col-frags)
    float padj[2][2][4];
#pragma unroll
    for (int f = 0; f < 2; ++f)
#pragma unroll
      for (int r = 0; r < 4; ++r) {
        float mx = fmaxf(sv[f][0][r], sv[f][1][r]);
#pragma unroll
        for (int d2 = 1; d2 < 16; d2 <<= 1) mx = fmaxf(mx, __shfl_xor(mx, d2));
        const float mn = fmaxf(mrun[f][r], mx);
        const float alpha = __expf(mrun[f][r] - mn);
        mrun[f][r] = mn;
        float ps = 0.f;
#pragma unroll
        for (int c = 0; c < 2; ++c) {
          const float p = (aw[f][c][r] > 0.f) ? __expf(sv[f][c][r] - mn) : 0.f;
          padj[f][c][r] = p * aw[f][c][r];
          ps += p;
        }
#pragma unroll
        for (int d2 = 1; d2 < 16; d2 <<= 1) ps += __shfl_xor(ps, d2);
        lrun[f][r] = lrun[f][r] * alpha + ps;
#pragma unroll
        for (int c2 = 0; c2 < 4; ++c2) o[f][c2][r] *= alpha;
      }

    // P*adj -> LDS (bf16), then reread as A-fragments for PV
    __syncthreads();
#pragma unroll
    for (int f = 0; f < 2; ++f)
#pragma unroll
      for (int c = 0; c < 2; ++c)
#pragma unroll
        for (int r = 0; r < 4; ++r)
          Pl[(16 * f + 4 * g + r) * 40 + 16 * c + l15] = f2bf(padj[f][c][r]);
    __syncthreads();
    short8 pA[2];
#pragma unroll
    for (int f = 0; f < 2; ++f)
      pA[f] = *(const short8*)(Pl + (16 * f + l15) * 40 + g * 8);
#pragma unroll
    for (int f = 0; f < 2; ++f)
#pragma unroll
      for (int c2 = 0; c2 < 4; ++c2)
        o[f][c2] = __builtin_amdgcn_mfma_f32_16x16x32_bf16(pA[f], vB[c2], o[f][c2], 0, 0, 0);
  }

  // epilogue: divide by unadjusted softmax sum; write concat layout bf16
#pragma unroll
  for (int f = 0; f < 2; ++f)
#pragma unroll
    for (int r = 0; r < 4; ++r) {
      const float inv = lrun[f][r] > 0.f ? 1.0f / lrun[f][r] : 0.f;
      const int qi = q0 + 16 * f + 4 * g + r;
#pragma unroll
      for (int c2 = 0; c2 < 4; ++c2)
        outc[((size_t)b * 1024 + qi) * 512 + h * 64 + 16 * c2 + l15] =
            f2bf(o[f][c2][r] * inv);
    }
}

// ---------- launch ----------
extern "C" void kernel_launch(void* const* d_in, const int* in_sizes, int n_in,
                              void* d_out, int out_size, void* d_ws, size_t ws_size,
                              hipStream_t stream) {
  (void)in_sizes; (void)n_in; (void)out_size; (void)ws_size;
  const float* q    = (const float*)d_in[0];
  const float* k    = (const float*)d_in[1];
  const float* v    = (const float*)d_in[2];
  const int*  q_seq = (const int*)d_in[3];
  const int*  c_seq = (const int*)d_in[4];
  const float* Wq   = (const float*)d_in[5];
  const float* bq   = (const float*)d_in[6];
  const float* Wk   = (const float*)d_in[7];
  const float* bk   = (const float*)d_in[8];
  const float* Wv   = (const float*)d_in[9];
  const float* bv   = (const float*)d_in[10];
  const float* Wo   = (const float*)d_in[11];
  const float* bo   = (const float*)d_in[12];
  float* out = (float*)d_out;

  char* ws = (char*)d_ws;
  const size_t SZH = 16ull * 8 * 1024 * 64 * 2;   // 16.78 MB per [B][H][S][64] bf16
  u16* qhb = (u16*)(ws + 0 * SZH);
  u16* khb = (u16*)(ws + 1 * SZH);
  u16* vTb = (u16*)(ws + 2 * SZH);
  u16* qb  = (u16*)(ws + 3 * SZH);                // bf16(q); later reused as attn concat
  u16* kb  = (u16*)(ws + 4 * SZH);
  u16* vb  = (u16*)(ws + 5 * SZH);
  u16* attnc = qb;                                 // alias: q_bf16 dead after proj GEMM
  u16* Wvb = (u16*)(ws + 6 * SZH + 0 * 524288);
  u16* Wkb = (u16*)(ws + 6 * SZH + 1 * 524288);
  u16* Wqb = (u16*)(ws + 6 * SZH + 2 * 524288);
  u16* Wob = (u16*)(ws + 6 * SZH + 3 * 524288);
  int2* meta = (int2*)(ws + 6 * SZH + 4 * 524288);

  const int n8big = 16384 * 512 / 8;   // 1048576
  const int n8w   = 512 * 512 / 8;     // 32768
  cast_kernel<<<n8big / 256, 256, 0, stream>>>(q, qb, n8big);
  cast_kernel<<<n8big / 256, 256, 0, stream>>>(k, kb, n8big);
  cast_kernel<<<n8big / 256, 256, 0, stream>>>(v, vb, n8big);
  cast_kernel<<<n8w / 256, 256, 0, stream>>>(Wv, Wvb, n8w);
  cast_kernel<<<n8w / 256, 256, 0, stream>>>(Wk, Wkb, n8w);
  cast_kernel<<<n8w / 256, 256, 0, stream>>>(Wq, Wqb, n8w);
  cast_kernel<<<n8w / 256, 256, 0, stream>>>(Wo, Wob, n8w);
  pack_kernel<<<64, 256, 0, stream>>>(q_seq, c_seq, meta, 16384);

  const int M = 16384, N = 512, K = 512;
  dim3 gg(512);
  // NB reference's weight shuffle: qh uses Wv/bv, kh uses Wk/bk, vh uses Wq/bq
  gemm_bt<0><<<gg, 256, 0, stream>>>(qb, Wvb, bv, qhb, M, N, K);
  gemm_bt<0><<<gg, 256, 0, stream>>>(kb, Wkb, bk, khb, M, N, K);
  gemm_bt<1><<<gg, 256, 0, stream>>>(vb, Wqb, bq, vTb, M, N, K);
  attn_kernel<<<dim3(32, 8, 16), 64, 0, stream>>>(qhb, khb, vTb, meta, attnc);
  gemm_bt<2><<<gg, 256, 0, stream>>>(attnc, Wob, bo, out, M, N, K);
}

// Round 2
// 238.850 us; speedup vs baseline: 1.3707x; 1.3707x over previous
//
#include <hip/hip_runtime.h>
#include <stdint.h>

typedef unsigned short u16;
typedef unsigned int   u32;
typedef __attribute__((ext_vector_type(8))) short short8;   // 8 x bf16 fragment
typedef __attribute__((ext_vector_type(4))) float f32x4;    // MFMA accumulator

// ---------- helpers ----------
__device__ __forceinline__ u16 f2bf(float f) {          // RNE f32 -> bf16
  u32 u = __builtin_bit_cast(u32, f);
  u32 r = u + 0x7FFFu + ((u >> 16) & 1u);
  return (u16)(r >> 16);
}

// async global->LDS, 16B per lane (dest must be wave-uniform base + lane*16)
__device__ __forceinline__ void gload_lds16(const void* g, void* l) {
  __builtin_amdgcn_global_load_lds(
      (__attribute__((address_space(1))) void*)(uintptr_t)g,
      (__attribute__((address_space(3))) void*)(u32)(uintptr_t)l,
      16, 0, 0);
}

// ---------- elementwise f32 -> bf16 cast (8 elems/thread) ----------
__global__ void cast_kernel(const float* __restrict__ src, u16* __restrict__ dst, int n8) {
  int i = blockIdx.x * blockDim.x + threadIdx.x;
  if (i >= n8) return;
  const float4* s4 = (const float4*)src;
  float4 x = s4[2 * (size_t)i];
  float4 y = s4[2 * (size_t)i + 1];
  union { u16 u[8]; uint4 v; } r;
  r.u[0] = f2bf(x.x); r.u[1] = f2bf(x.y); r.u[2] = f2bf(x.z); r.u[3] = f2bf(x.w);
  r.u[4] = f2bf(y.x); r.u[5] = f2bf(y.y); r.u[6] = f2bf(y.z); r.u[7] = f2bf(y.w);
  *(uint4*)(dst + 8 * (size_t)i) = r.v;
}

// ---------- pack {q_seq, c_bits} per position ----------
__global__ void pack_kernel(const int* __restrict__ q_seq, const int* __restrict__ c_seq,
                            int2* __restrict__ meta, int n) {
  int i = blockIdx.x * blockDim.x + threadIdx.x;
  if (i >= n) return;
  u32 bits = 0;
#pragma unroll
  for (int j = 0; j < 32; ++j)
    bits |= (c_seq[(size_t)i * 32 + j] != 0) ? (1u << j) : 0u;
  meta[i] = make_int2(q_seq[i], (int)bits);
}

// ---------- GEMM: C[m][n] = sum_k A[m][k]*W[n][k] + bias[n] ----------
// A: bf16 [M][K]; W: bf16 [N][K] (row n = output col, K-contiguous = B^T layout)
// MODE 0: store bf16 to [b][h][s][64]   (b=row>>10, s=row&1023, h=col>>6, d=col&63)
// MODE 1: store bf16 to [b][h][64][1024] (V transposed)
// MODE 2: store f32 to [row][col] (row-major, N=512)
template <int MODE>
__global__ __launch_bounds__(256) void gemm_bt(const u16* __restrict__ A,
                                               const u16* __restrict__ W,
                                               const float* __restrict__ bias,
                                               void* __restrict__ outp,
                                               int M, int N, int K) {
  __shared__ __align__(16) u16 As[128 * 64];
  __shared__ __align__(16) u16 Bs[128 * 64];
  const int t    = threadIdx.x;
  const int lane = t & 63;
  const int wid  = t >> 6;
  const int g    = lane >> 4, l15 = lane & 15;
  const int wm   = wid >> 1, wn = wid & 1;           // 2x2 wave grid, 64x64 per wave
  const int nb   = N >> 7;
  const int mb   = blockIdx.x / nb, nbi = blockIdx.x % nb;
  const int m0   = mb << 7, n0 = nbi << 7;
  const int srow = t >> 3;                            // staging row within 32-row slab
  const int scol = (t & 7) << 3;                      // staging col (elements)

  f32x4 acc[4][4];
#pragma unroll
  for (int i = 0; i < 4; ++i)
#pragma unroll
    for (int j = 0; j < 4; ++j) acc[i][j] = f32x4{0.f, 0.f, 0.f, 0.f};

  for (int k0 = 0; k0 < K; k0 += 64) {
    __syncthreads();                                  // protect LDS from prev-iter reads
#pragma unroll
    for (int i = 0; i < 4; ++i) {
      const u16* sa = A + (size_t)(m0 + i * 32 + srow) * K + k0 + scol;
      const u16* sb = W + (size_t)(n0 + i * 32 + srow) * K + k0 + scol;
      gload_lds16(sa, As + i * 2048 + t * 8);
      gload_lds16(sb, Bs + i * 2048 + t * 8);
    }
    __syncthreads();                                  // drains vmcnt for global_load_lds
#pragma unroll
    for (int kk = 0; kk < 2; ++kk) {
      short8 a[4], b[4];
#pragma unroll
      for (int mi = 0; mi < 4; ++mi)
        a[mi] = *(const short8*)(As + (wm * 64 + mi * 16 + l15) * 64 + kk * 32 + g * 8);
#pragma unroll
      for (int ni = 0; ni < 4; ++ni)
        b[ni] = *(const short8*)(Bs + (wn * 64 + ni * 16 + l15) * 64 + kk * 32 + g * 8);
#pragma unroll
      for (int mi = 0; mi < 4; ++mi)
#pragma unroll
        for (int ni = 0; ni < 4; ++ni)
          acc[mi][ni] = __builtin_amdgcn_mfma_f32_16x16x32_bf16(a[mi], b[ni], acc[mi][ni], 0, 0, 0);
    }
  }

#pragma unroll
  for (int ni = 0; ni < 4; ++ni) {
    const int col = n0 + wn * 64 + ni * 16 + l15;
    const float bz = bias[col];
#pragma unroll
    for (int mi = 0; mi < 4; ++mi) {
#pragma unroll
      for (int r = 0; r < 4; ++r) {
        const int row = m0 + wm * 64 + mi * 16 + g * 4 + r;   // C/D: row=(lane>>4)*4+reg
        const float val = acc[mi][ni][r] + bz;
        if (MODE == 2) {
          ((float*)outp)[(size_t)row * N + col] = val;
        } else if (MODE == 0) {
          const size_t ad = ((size_t)(row >> 10) * 8 + (col >> 6)) * 65536
                          + (size_t)(row & 1023) * 64 + (col & 63);
          ((u16*)outp)[ad] = f2bf(val);
        } else {
          const size_t ad = ((size_t)(row >> 10) * 8 + (col >> 6)) * 65536
                          + (size_t)(col & 63) * 1024 + (row & 1023);
          ((u16*)outp)[ad] = f2bf(val);
        }
      }
    }
  }
}

// ---------- flash attention with QC mask + post-softmax adjustment ----------
// Round 2: no-online-max softmax (scores bounded; clamp at 60 as insurance),
// KVBLK=64, 4 independent waves/block (own q-tile, own causal bound, no
// barriers), per-wave LDS P buffer stride 72 u16 (16B-aligned rows, uniform
// bank-quad spread for ds_read_b128). All cross-lane shfls hoisted to epilogue.
// grid (H=8, S/128=8, B=16), 256 threads. qh,kh: [b][h][1024][64] bf16;
// vT: [b][h][64][1024] bf16; outc: [b*1024+s][512] bf16
__global__ __launch_bounds__(256) void attn_kernel(const u16* __restrict__ qh,
                                                   const u16* __restrict__ kh,
                                                   const u16* __restrict__ vT,
                                                   const int2* __restrict__ meta,
                                                   u16* __restrict__ outc) {
  const int h  = blockIdx.x;
  const int qb = 7 - blockIdx.y;          // heavy (high-q) blocks dispatch first
  const int b  = blockIdx.z;
  const int lane = threadIdx.x & 63;
  const int wid  = threadIdx.x >> 6;
  const int g = lane >> 4, l15 = lane & 15;
  const int q0 = qb * 128 + wid * 32;     // this wave's 32 q rows
  const size_t bh = (size_t)b * 8 + h;
  const u16* Q  = qh + bh * 65536;
  const u16* Kp = kh + bh * 65536;
  const u16* Vt = vT + bh * 65536;
  const int2* mb_ = meta + b * 1024;

  __shared__ __align__(16) u16 Pl_all[4][32 * 72];
  u16* Pl = Pl_all[wid];                  // wave-private: no block barriers needed

  // Q A-fragments: row = lane&15, k = 8*(lane>>4)+i
  short8 qA[2][2];
#pragma unroll
  for (int f = 0; f < 2; ++f)
#pragma unroll
    for (int kk = 0; kk < 2; ++kk)
      qA[f][kk] = *(const short8*)(Q + (size_t)(q0 + 16 * f + l15) * 64 + kk * 32 + g * 8);

  int rs[2][4]; u32 rb[2][4];
#pragma unroll
  for (int f = 0; f < 2; ++f)
#pragma unroll
    for (int r = 0; r < 4; ++r) {
      int2 mm = mb_[q0 + 16 * f + 4 * g + r];
      rs[f][r] = mm.x; rb[f][r] = (u32)mm.y;
    }

  float lrun[2][4];
  f32x4 o[2][4];
#pragma unroll
  for (int f = 0; f < 2; ++f) {
#pragma unroll
    for (int r = 0; r < 4; ++r) lrun[f][r] = 0.f;
#pragma unroll
    for (int c2 = 0; c2 < 4; ++c2) o[f][c2] = f32x4{0.f, 0.f, 0.f, 0.f};
  }
  const f32x4 fzero = {0.f, 0.f, 0.f, 0.f};

  const int nt = (q0 >> 6) + 1;           // causal: need k <= q0+30
  for (int t = 0; t < nt; ++t) {
    const int k0 = t << 6;

    int cs[4]; u32 cb[4];
#pragma unroll
    for (int c = 0; c < 4; ++c) {
      int2 mm = mb_[k0 + 16 * c + l15];
      cs[c] = mm.x; cb[c] = (u32)mm.y;
    }
    short8 kB[4][2];
#pragma unroll
    for (int c = 0; c < 4; ++c)
#pragma unroll
      for (int kk = 0; kk < 2; ++kk)
        kB[c][kk] = *(const short8*)(Kp + (size_t)(k0 + 16 * c + l15) * 64 + kk * 32 + g * 8);

#pragma unroll
    for (int f = 0; f < 2; ++f) {
      f32x4 sfr[4];
#pragma unroll
      for (int c = 0; c < 4; ++c) {
        f32x4 tmp = __builtin_amdgcn_mfma_f32_16x16x32_bf16(qA[f][0], kB[c][0], fzero, 0, 0, 0);
        sfr[c] = __builtin_amdgcn_mfma_f32_16x16x32_bf16(qA[f][1], kB[c][1], tmp, 0, 0, 0);
      }
      // mask + exp + adjust + accumulate l; write P*adj (bf16) to wave LDS
#pragma unroll
      for (int c = 0; c < 4; ++c) {
        const int kj = k0 + 16 * c + l15;
#pragma unroll
        for (int r = 0; r < 4; ++r) {
          const int qi = q0 + 16 * f + 4 * g + r;
          const bool vis = kj < qi;
          float p = vis ? __expf(fminf(sfr[c][r] * 0.125f, 60.f)) : 0.f;
          const float t1 = ((rb[f][r] & cb[c]) != 0u) ? 1.f : 0.5f;
          const float aw = (rs[f][r] == cs[c]) ? 2.f * t1 : t1;
          lrun[f][r] += p;
          Pl[(16 * f + 4 * g + r) * 72 + 16 * c + l15] = f2bf(p * aw);
        }
      }
    }

    short8 vB[4][2];
#pragma unroll
    for (int c2 = 0; c2 < 4; ++c2)
#pragma unroll
      for (int kk = 0; kk < 2; ++kk)
        vB[c2][kk] = *(const short8*)(Vt + (size_t)(16 * c2 + l15) * 1024 + k0 + kk * 32 + g * 8);

    // ensure P writes landed (wave-private; LDS in-order, belt & braces)
    asm volatile("s_waitcnt lgkmcnt(0)" ::: "memory");

    short8 pA[2][2];
#pragma unroll
    for (int f = 0; f < 2; ++f)
#pragma unroll
      for (int kk = 0; kk < 2; ++kk)
        pA[f][kk] = *(const short8*)(Pl + (16 * f + l15) * 72 + kk * 32 + g * 8);

#pragma unroll
    for (int f = 0; f < 2; ++f)
#pragma unroll
      for (int c2 = 0; c2 < 4; ++c2) {
        o[f][c2] = __builtin_amdgcn_mfma_f32_16x16x32_bf16(pA[f][0], vB[c2][0], o[f][c2], 0, 0, 0);
        o[f][c2] = __builtin_amdgcn_mfma_f32_16x16x32_bf16(pA[f][1], vB[c2][1], o[f][c2], 0, 0, 0);
      }
  }

  // epilogue: reduce l across the 16-lane column group (once per kernel)
#pragma unroll
  for (int f = 0; f < 2; ++f)
#pragma unroll
    for (int r = 0; r < 4; ++r) {
      float s = lrun[f][r];
#pragma unroll
      for (int d2 = 1; d2 < 16; d2 <<= 1) s += __shfl_xor(s, d2);
      const float inv = s > 0.f ? 1.0f / s : 0.f;
      const int qi = q0 + 16 * f + 4 * g + r;
#pragma unroll
      for (int c2 = 0; c2 < 4; ++c2)
        outc[((size_t)b * 1024 + qi) * 512 + h * 64 + 16 * c2 + l15] =
            f2bf(o[f][c2][r] * inv);
    }
}

// ---------- launch ----------
extern "C" void kernel_launch(void* const* d_in, const int* in_sizes, int n_in,
                              void* d_out, int out_size, void* d_ws, size_t ws_size,
                              hipStream_t stream) {
  (void)in_sizes; (void)n_in; (void)out_size; (void)ws_size;
  const float* q    = (const float*)d_in[0];
  const float* k    = (const float*)d_in[1];
  const float* v    = (const float*)d_in[2];
  const int*  q_seq = (const int*)d_in[3];
  const int*  c_seq = (const int*)d_in[4];
  const float* Wq   = (const float*)d_in[5];
  const float* bq   = (const float*)d_in[6];
  const float* Wk   = (const float*)d_in[7];
  const float* bk   = (const float*)d_in[8];
  const float* Wv   = (const float*)d_in[9];
  const float* bv   = (const float*)d_in[10];
  const float* Wo   = (const float*)d_in[11];
  const float* bo   = (const float*)d_in[12];
  float* out = (float*)d_out;

  char* ws = (char*)d_ws;
  const size_t SZH = 16ull * 8 * 1024 * 64 * 2;   // 16.78 MB per [B][H][S][64] bf16
  u16* qhb = (u16*)(ws + 0 * SZH);
  u16* khb = (u16*)(ws + 1 * SZH);
  u16* vTb = (u16*)(ws + 2 * SZH);
  u16* qb  = (u16*)(ws + 3 * SZH);                // bf16(q); later reused as attn concat
  u16* kb  = (u16*)(ws + 4 * SZH);
  u16* vb  = (u16*)(ws + 5 * SZH);
  u16* attnc = qb;                                 // alias: q_bf16 dead after proj GEMM
  u16* Wvb = (u16*)(ws + 6 * SZH + 0 * 524288);
  u16* Wkb = (u16*)(ws + 6 * SZH + 1 * 524288);
  u16* Wqb = (u16*)(ws + 6 * SZH + 2 * 524288);
  u16* Wob = (u16*)(ws + 6 * SZH + 3 * 524288);
  int2* meta = (int2*)(ws + 6 * SZH + 4 * 524288);

  const int n8big = 16384 * 512 / 8;   // 1048576
  const int n8w   = 512 * 512 / 8;     // 32768
  cast_kernel<<<n8big / 256, 256, 0, stream>>>(q, qb, n8big);
  cast_kernel<<<n8big / 256, 256, 0, stream>>>(k, kb, n8big);
  cast_kernel<<<n8big / 256, 256, 0, stream>>>(v, vb, n8big);
  cast_kernel<<<n8w / 256, 256, 0, stream>>>(Wv, Wvb, n8w);
  cast_kernel<<<n8w / 256, 256, 0, stream>>>(Wk, Wkb, n8w);
  cast_kernel<<<n8w / 256, 256, 0, stream>>>(Wq, Wqb, n8w);
  cast_kernel<<<n8w / 256, 256, 0, stream>>>(Wo, Wob, n8w);
  pack_kernel<<<64, 256, 0, stream>>>(q_seq, c_seq, meta, 16384);

  const int M = 16384, N = 512, K = 512;
  dim3 gg(512);
  // NB reference's weight shuffle: qh uses Wv/bv, kh uses Wk/bk, vh uses Wq/bq
  gemm_bt<0><<<gg, 256, 0, stream>>>(qb, Wvb, bv, qhb, M, N, K);
  gemm_bt<0><<<gg, 256, 0, stream>>>(kb, Wkb, bk, khb, M, N, K);
  gemm_bt<1><<<gg, 256, 0, stream>>>(vb, Wqb, bq, vTb, M, N, K);
  attn_kernel<<<dim3(8, 8, 16), 256, 0, stream>>>(qhb, khb, vTb, meta, attnc);
  gemm_bt<2><<<gg, 256, 0, stream>>>(attnc, Wob, bo, out, M, N, K);
}

// Round 3
// 224.975 us; speedup vs baseline: 1.4552x; 1.0617x over previous
//
#include <hip/hip_runtime.h>
#include <stdint.h>

typedef unsigned short u16;
typedef unsigned int   u32;
typedef __attribute__((ext_vector_type(8)))  short short8;   // 8 x bf16 fragment
typedef __attribute__((ext_vector_type(4)))  float f32x4;
typedef __attribute__((ext_vector_type(16))) float f32x16;   // 32x32 MFMA accumulator
typedef __attribute__((ext_vector_type(4)))  unsigned int u32x4;

// ---------- helpers ----------
__device__ __forceinline__ u16 f2bf(float f) {          // RNE f32 -> bf16
  u32 u = __builtin_bit_cast(u32, f);
  u32 r = u + 0x7FFFu + ((u >> 16) & 1u);
  return (u16)(r >> 16);
}

// async global->LDS, 16B per lane (dest must be wave-uniform base + lane*16)
__device__ __forceinline__ void gload_lds16(const void* g, void* l) {
  __builtin_amdgcn_global_load_lds(
      (__attribute__((address_space(1))) void*)(uintptr_t)g,
      (__attribute__((address_space(3))) void*)(u32)(uintptr_t)l,
      16, 0, 0);
}

// ---------- elementwise f32 -> bf16 cast (8 elems/thread) ----------
__global__ void cast_kernel(const float* __restrict__ src, u16* __restrict__ dst, int n8) {
  int i = blockIdx.x * blockDim.x + threadIdx.x;
  if (i >= n8) return;
  const float4* s4 = (const float4*)src;
  float4 x = s4[2 * (size_t)i];
  float4 y = s4[2 * (size_t)i + 1];
  union { u16 u[8]; uint4 v; } r;
  r.u[0] = f2bf(x.x); r.u[1] = f2bf(x.y); r.u[2] = f2bf(x.z); r.u[3] = f2bf(x.w);
  r.u[4] = f2bf(y.x); r.u[5] = f2bf(y.y); r.u[6] = f2bf(y.z); r.u[7] = f2bf(y.w);
  *(uint4*)(dst + 8 * (size_t)i) = r.v;
}

// ---------- pack {q_seq, c_bits} per position ----------
__global__ void pack_kernel(const int* __restrict__ q_seq, const int* __restrict__ c_seq,
                            int2* __restrict__ meta, int n) {
  int i = blockIdx.x * blockDim.x + threadIdx.x;
  if (i >= n) return;
  u32 bits = 0;
#pragma unroll
  for (int j = 0; j < 32; ++j)
    bits |= (c_seq[(size_t)i * 32 + j] != 0) ? (1u << j) : 0u;
  meta[i] = make_int2(q_seq[i], (int)bits);
}

// ---------- GEMM: C[m][n] = (sum_k A[m][k]*W[n][k] + bias[n]) * scale ----------
// A: bf16 [M][K]; W: bf16 [N][K]
// MODE 0: store bf16 to [b][h][s][64];  MODE 1: bf16 [b][h][64][1024] (V^T);
// MODE 2: f32 row-major [M][N]
template <int MODE>
__global__ __launch_bounds__(256) void gemm_bt(const u16* __restrict__ A,
                                               const u16* __restrict__ W,
                                               const float* __restrict__ bias,
                                               void* __restrict__ outp,
                                               int M, int N, int K, float scale) {
  __shared__ __align__(16) u16 As[128 * 64];
  __shared__ __align__(16) u16 Bs[128 * 64];
  const int t    = threadIdx.x;
  const int lane = t & 63;
  const int wid  = t >> 6;
  const int g    = lane >> 4, l15 = lane & 15;
  const int wm   = wid >> 1, wn = wid & 1;
  const int nb   = N >> 7;
  const int mb   = blockIdx.x / nb, nbi = blockIdx.x % nb;
  const int m0   = mb << 7, n0 = nbi << 7;
  const int srow = t >> 3;
  const int scol = (t & 7) << 3;

  f32x4 acc[4][4];
#pragma unroll
  for (int i = 0; i < 4; ++i)
#pragma unroll
    for (int j = 0; j < 4; ++j) acc[i][j] = f32x4{0.f, 0.f, 0.f, 0.f};

  for (int k0 = 0; k0 < K; k0 += 64) {
    __syncthreads();
#pragma unroll
    for (int i = 0; i < 4; ++i) {
      const u16* sa = A + (size_t)(m0 + i * 32 + srow) * K + k0 + scol;
      const u16* sb = W + (size_t)(n0 + i * 32 + srow) * K + k0 + scol;
      gload_lds16(sa, As + i * 2048 + t * 8);
      gload_lds16(sb, Bs + i * 2048 + t * 8);
    }
    __syncthreads();
#pragma unroll
    for (int kk = 0; kk < 2; ++kk) {
      short8 a[4], b[4];
#pragma unroll
      for (int mi = 0; mi < 4; ++mi)
        a[mi] = *(const short8*)(As + (wm * 64 + mi * 16 + l15) * 64 + kk * 32 + g * 8);
#pragma unroll
      for (int ni = 0; ni < 4; ++ni)
        b[ni] = *(const short8*)(Bs + (wn * 64 + ni * 16 + l15) * 64 + kk * 32 + g * 8);
#pragma unroll
      for (int mi = 0; mi < 4; ++mi)
#pragma unroll
        for (int ni = 0; ni < 4; ++ni)
          acc[mi][ni] = __builtin_amdgcn_mfma_f32_16x16x32_bf16(a[mi], b[ni], acc[mi][ni], 0, 0, 0);
    }
  }

#pragma unroll
  for (int ni = 0; ni < 4; ++ni) {
    const int col = n0 + wn * 64 + ni * 16 + l15;
    const float bz = bias[col];
#pragma unroll
    for (int mi = 0; mi < 4; ++mi) {
#pragma unroll
      for (int r = 0; r < 4; ++r) {
        const int row = m0 + wm * 64 + mi * 16 + g * 4 + r;
        const float val = (acc[mi][ni][r] + bz) * scale;
        if (MODE == 2) {
          ((float*)outp)[(size_t)row * N + col] = val;
        } else if (MODE == 0) {
          const size_t ad = ((size_t)(row >> 10) * 8 + (col >> 6)) * 65536
                          + (size_t)(row & 1023) * 64 + (col & 63);
          ((u16*)outp)[ad] = f2bf(val);
        } else {
          const size_t ad = ((size_t)(row >> 10) * 8 + (col >> 6)) * 65536
                          + (size_t)(col & 63) * 1024 + (row & 1023);
          ((u16*)outp)[ad] = f2bf(val);
        }
      }
    }
  }
}

// ---------- flash attention, swapped-QK 32x32, all-register softmax ----------
// S' = mfma32(K,Q): lane owns q = lane&31; k = (m&3)+8*(m>>2)+4*(lane>>5)+32c.
// P->bf16 via v_cvt_pk_bf16_f32, redistributed to PV A-frags via
// v_permlane32_swap_b32 (no LDS for P). K pre-scaled by log2(e)/8 => p=2^s.
// Wave w of block qb takes q-tile j=8w+qb (load balance). grid (h, qb, b).
__global__ __launch_bounds__(256, 3) void attn_kernel(const u16* __restrict__ qh,
                                                      const u16* __restrict__ kh,
                                                      const u16* __restrict__ vT,
                                                      const int2* __restrict__ meta,
                                                      u16* __restrict__ outc) {
  const int h  = blockIdx.x;
  const int qb = blockIdx.y;
  const int b  = blockIdx.z;
  const int lane = threadIdx.x & 63;
  const int wid  = threadIdx.x >> 6;
  const int l31 = lane & 31;
  const int hh  = lane >> 5;
  const int fourh = hh << 2, eighth = hh << 3;
  const int jt = wid * 8 + qb;            // q-tile index 0..31
  const int q0 = jt << 5;
  const int qi = q0 + l31;                // this lane's q row
  const size_t bh = (size_t)b * 8 + h;
  const u16* Q  = qh + bh * 65536;
  const u16* Kp = kh + bh * 65536;
  const u16* Vt = vT + bh * 65536;
  const int2* mb_ = meta + b * 1024;

  __shared__ __align__(16) float Sl[4][32];

  // Q as B-fragments (col = q = l31, k-dim = d)
  short8 qB[4];
#pragma unroll
  for (int i = 0; i < 4; ++i)
    qB[i] = *(const short8*)(Q + (size_t)qi * 64 + i * 16 + eighth);

  const int2 qm = mb_[qi];
  const int rs = qm.x;
  const u32 rb = (u32)qm.y;

  f32x16 O0, O1;
#pragma unroll
  for (int i = 0; i < 16; ++i) { O0[i] = 0.f; O1[i] = 0.f; }
  float lrun = 0.f;

  const int nt = (jt >> 1) + 1;

  // K as A-fragments (row = k-local = l31), prologue tile 0
  short8 kA[2][4];
#pragma unroll
  for (int c = 0; c < 2; ++c)
#pragma unroll
    for (int i = 0; i < 4; ++i)
      kA[c][i] = *(const short8*)(Kp + (size_t)(32 * c + l31) * 64 + i * 16 + eighth);

  for (int t = 0; t < nt; ++t) {
    const int k0 = t << 6;

    // S' = K Q^T (two 32-k subtiles, chained over d=64)
    f32x16 z;
#pragma unroll
    for (int i = 0; i < 16; ++i) z[i] = 0.f;
    f32x16 S0 = z, S1 = z;
#pragma unroll
    for (int i = 0; i < 4; ++i)
      S0 = __builtin_amdgcn_mfma_f32_32x32x16_bf16(kA[0][i], qB[i], S0, 0, 0, 0);
#pragma unroll
    for (int i = 0; i < 4; ++i)
      S1 = __builtin_amdgcn_mfma_f32_32x32x16_bf16(kA[1][i], qB[i], S1, 0, 0, 0);

    // prefetch next K tile into same regs (consumed above)
    if (t + 1 < nt) {
      const int k0n = k0 + 64;
#pragma unroll
      for (int c = 0; c < 2; ++c)
#pragma unroll
        for (int i = 0; i < 4; ++i)
          kA[c][i] = *(const short8*)(Kp + (size_t)(k0n + 32 * c + l31) * 64 + i * 16 + eighth);
    }

    // softmax: p = 2^s (K pre-scaled), mask, adjust, pack to bf16 pairs
    u32 pk[16];
#pragma unroll
    for (int c = 0; c < 2; ++c) {
      const f32x16 S = c ? S1 : S0;
#pragma unroll
      for (int t2 = 0; t2 < 4; ++t2) {
        const int2* mp = mb_ + (k0 + 32 * c + 8 * t2 + fourh);
        const int4 me0 = *(const int4*)mp;         // (cs,cb) for k+0, k+1
        const int4 me1 = *(const int4*)(mp + 2);   // (cs,cb) for k+2, k+3
        float pv[4];
#pragma unroll
        for (int r = 0; r < 4; ++r) {
          const int m = 4 * t2 + r;
          const int cs = (r == 0) ? me0.x : (r == 1) ? me0.z : (r == 2) ? me1.x : me1.z;
          const u32 cb = (u32)((r == 0) ? me0.y : (r == 1) ? me0.w : (r == 2) ? me1.y : me1.w);
          const int kj = k0 + 32 * c + 8 * t2 + r + fourh;
          float e;
          asm("v_exp_f32 %0, %1" : "=v"(e) : "v"(S[m]));
          const float p = (kj < qi) ? e : 0.f;
          lrun += p;
          const float t1 = ((rb & cb) != 0u) ? 1.f : 0.5f;
          const float aw = (rs == cs) ? t1 + t1 : t1;
          pv[r] = p * aw;
        }
        u32 w0, w1;
        asm("v_cvt_pk_bf16_f32 %0, %1, %2" : "=v"(w0) : "v"(pv[0]), "v"(pv[1]));
        asm("v_cvt_pk_bf16_f32 %0, %1, %2" : "=v"(w1) : "v"(pv[2]), "v"(pv[3]));
        pk[c * 8 + 2 * t2]     = w0;
        pk[c * 8 + 2 * t2 + 1] = w1;
      }
    }

    // PV: build A-frags via permlane32_swap; chunk t4 = 16 k
#pragma unroll
    for (int t4 = 0; t4 < 4; ++t4) {
      const int c = t4 >> 1, tl = t4 & 1;
      u32 a0 = pk[c * 8 + 4 * tl + 0], b0 = pk[c * 8 + 4 * tl + 2];
      u32 a1 = pk[c * 8 + 4 * tl + 1], b1 = pk[c * 8 + 4 * tl + 3];
      asm("v_permlane32_swap_b32 %0, %1" : "+v"(a0), "+v"(b0));
      asm("v_permlane32_swap_b32 %0, %1" : "+v"(a1), "+v"(b1));
      u32x4 w; w.x = a0; w.y = a1; w.z = b0; w.w = b1;
      const short8 pa = __builtin_bit_cast(short8, w);
      const short8 v0 = *(const short8*)(Vt + (size_t)l31 * 1024 + k0 + t4 * 16 + eighth);
      const short8 v1 = *(const short8*)(Vt + (size_t)(32 + l31) * 1024 + k0 + t4 * 16 + eighth);
      O0 = __builtin_amdgcn_mfma_f32_32x32x16_bf16(pa, v0, O0, 0, 0, 0);
      O1 = __builtin_amdgcn_mfma_f32_32x32x16_bf16(pa, v1, O1, 0, 0, 0);
    }
  }

  // epilogue: full row-sum (h-halves), broadcast 1/l via tiny LDS, write out
  const float ssum = lrun + __shfl_xor(lrun, 32);
  if (lane < 32) Sl[wid][l31] = (ssum > 0.f) ? 1.f / ssum : 0.f;
  __builtin_amdgcn_sched_barrier(0);
  asm volatile("s_waitcnt lgkmcnt(0)" ::: "memory");
  __builtin_amdgcn_sched_barrier(0);
#pragma unroll
  for (int t2 = 0; t2 < 4; ++t2) {
    const float4 inv4 = *(const float4*)&Sl[wid][8 * t2 + fourh];
#pragma unroll
    for (int r = 0; r < 4; ++r) {
      const int m = 4 * t2 + r;
      const float iv = (r == 0) ? inv4.x : (r == 1) ? inv4.y : (r == 2) ? inv4.z : inv4.w;
      const int qrow = q0 + 8 * t2 + fourh + r;
      u16* op = outc + ((size_t)b * 1024 + qrow) * 512 + h * 64;
      op[l31]      = f2bf(O0[m] * iv);
      op[32 + l31] = f2bf(O1[m] * iv);
    }
  }
}

// ---------- launch ----------
extern "C" void kernel_launch(void* const* d_in, const int* in_sizes, int n_in,
                              void* d_out, int out_size, void* d_ws, size_t ws_size,
                              hipStream_t stream) {
  (void)in_sizes; (void)n_in; (void)out_size; (void)ws_size;
  const float* q    = (const float*)d_in[0];
  const float* k    = (const float*)d_in[1];
  const float* v    = (const float*)d_in[2];
  const int*  q_seq = (const int*)d_in[3];
  const int*  c_seq = (const int*)d_in[4];
  const float* Wq   = (const float*)d_in[5];
  const float* bq   = (const float*)d_in[6];
  const float* Wk   = (const float*)d_in[7];
  const float* bk   = (const float*)d_in[8];
  const float* Wv   = (const float*)d_in[9];
  const float* bv   = (const float*)d_in[10];
  const float* Wo   = (const float*)d_in[11];
  const float* bo   = (const float*)d_in[12];
  float* out = (float*)d_out;

  char* ws = (char*)d_ws;
  const size_t SZH = 16ull * 8 * 1024 * 64 * 2;   // 16.78 MB per [B][H][S][64] bf16
  u16* qhb = (u16*)(ws + 0 * SZH);
  u16* khb = (u16*)(ws + 1 * SZH);
  u16* vTb = (u16*)(ws + 2 * SZH);
  u16* qb  = (u16*)(ws + 3 * SZH);
  u16* kb  = (u16*)(ws + 4 * SZH);
  u16* vb  = (u16*)(ws + 5 * SZH);
  u16* attnc = qb;                                 // alias: q_bf16 dead after proj GEMM
  u16* Wvb = (u16*)(ws + 6 * SZH + 0 * 524288);
  u16* Wkb = (u16*)(ws + 6 * SZH + 1 * 524288);
  u16* Wqb = (u16*)(ws + 6 * SZH + 2 * 524288);
  u16* Wob = (u16*)(ws + 6 * SZH + 3 * 524288);
  int2* meta = (int2*)(ws + 6 * SZH + 4 * 524288);

  const int n8big = 16384 * 512 / 8;
  const int n8w   = 512 * 512 / 8;
  cast_kernel<<<n8big / 256, 256, 0, stream>>>(q, qb, n8big);
  cast_kernel<<<n8big / 256, 256, 0, stream>>>(k, kb, n8big);
  cast_kernel<<<n8big / 256, 256, 0, stream>>>(v, vb, n8big);
  cast_kernel<<<n8w / 256, 256, 0, stream>>>(Wv, Wvb, n8w);
  cast_kernel<<<n8w / 256, 256, 0, stream>>>(Wk, Wkb, n8w);
  cast_kernel<<<n8w / 256, 256, 0, stream>>>(Wq, Wqb, n8w);
  cast_kernel<<<n8w / 256, 256, 0, stream>>>(Wo, Wob, n8w);
  pack_kernel<<<64, 256, 0, stream>>>(q_seq, c_seq, meta, 16384);

  const int M = 16384, N = 512, K = 512;
  dim3 gg(512);
  const float KSCALE = 0.18033688011112042f;   // log2(e)/8 -> softmax exp becomes 2^s
  // NB reference's weight shuffle: qh uses Wv/bv, kh uses Wk/bk, vh uses Wq/bq
  gemm_bt<0><<<gg, 256, 0, stream>>>(qb, Wvb, bv, qhb, M, N, K, 1.0f);
  gemm_bt<0><<<gg, 256, 0, stream>>>(kb, Wkb, bk, khb, M, N, K, KSCALE);
  gemm_bt<1><<<gg, 256, 0, stream>>>(vb, Wqb, bq, vTb, M, N, K, 1.0f);
  attn_kernel<<<dim3(8, 8, 16), 256, 0, stream>>>(qhb, khb, vTb, meta, attnc);
  gemm_bt<2><<<gg, 256, 0, stream>>>(attnc, Wob, bo, out, M, N, K, 1.0f);
}

// Round 4
// 200.416 us; speedup vs baseline: 1.6335x; 1.1225x over previous
//
#include <hip/hip_runtime.h>
#include <stdint.h>

typedef unsigned short u16;
typedef unsigned int   u32;
typedef unsigned long long u64;
typedef __attribute__((ext_vector_type(8)))  short short8;   // 8 x bf16 fragment
typedef __attribute__((ext_vector_type(4)))  float f32x4;
typedef __attribute__((ext_vector_type(16))) float f32x16;   // 32x32 MFMA accumulator
typedef __attribute__((ext_vector_type(4)))  unsigned int u32x4;

// ---------- helpers ----------
__device__ __forceinline__ u16 f2bf(float f) {          // RNE f32 -> bf16
  u32 u = __builtin_bit_cast(u32, f);
  u32 r = u + 0x7FFFu + ((u >> 16) & 1u);
  return (u16)(r >> 16);
}

__device__ __forceinline__ u32 cvtpk(float a, float b) { // 2xf32 -> packed bf16
  u32 r;
  asm("v_cvt_pk_bf16_f32 %0, %1, %2" : "=v"(r) : "v"(a), "v"(b));
  return r;
}

// async global->LDS, 16B per lane (dest must be wave-uniform base + lane*16)
__device__ __forceinline__ void gload_lds16(const void* g, void* l) {
  __builtin_amdgcn_global_load_lds(
      (__attribute__((address_space(1))) void*)(uintptr_t)g,
      (__attribute__((address_space(3))) void*)(u32)(uintptr_t)l,
      16, 0, 0);
}

// ---------- elementwise f32 -> bf16 cast (weights only now) ----------
__global__ void cast_kernel(const float* __restrict__ src, u16* __restrict__ dst, int n8) {
  int i = blockIdx.x * blockDim.x + threadIdx.x;
  if (i >= n8) return;
  const float4* s4 = (const float4*)src;
  float4 x = s4[2 * (size_t)i];
  float4 y = s4[2 * (size_t)i + 1];
  u32x4 r;
  r.x = cvtpk(x.x, x.y); r.y = cvtpk(x.z, x.w);
  r.z = cvtpk(y.x, y.y); r.w = cvtpk(y.z, y.w);
  *(u32x4*)(dst + 8 * (size_t)i) = r;
}

// ---------- pack {q_seq, c_bits} per position ----------
__global__ void pack_kernel(const int* __restrict__ q_seq, const int* __restrict__ c_seq,
                            int2* __restrict__ meta, int n) {
  int i = blockIdx.x * blockDim.x + threadIdx.x;
  if (i >= n) return;
  u32 bits = 0;
#pragma unroll
  for (int j = 0; j < 32; ++j)
    bits |= (c_seq[(size_t)i * 32 + j] != 0) ? (1u << j) : 0u;
  meta[i] = make_int2(q_seq[i], (int)bits);
}

// ---------- mask precompute: 2-bit m per (b, ktile32, q), tri included ----------
// maskw[b][kt][q] u64: bits 2j:2j+1 = m for k = kt*32+j; m = (k<q) ? 1+eq+ov : 0
__global__ __launch_bounds__(256) void mask_kernel(const int2* __restrict__ meta,
                                                   u64* __restrict__ maskw) {
  const int qc = blockIdx.x, kt = blockIdx.y, b = blockIdx.z;
  const int t = threadIdx.x;
  const int q = qc * 256 + t;
  __shared__ int2 colm[32];
  if (t < 32) colm[t] = meta[b * 1024 + kt * 32 + t];
  __syncthreads();
  const int2 qm = meta[b * 1024 + q];
  const int rs = qm.x; const u32 rb = (u32)qm.y;
  u64 w = 0;
#pragma unroll
  for (int j = 0; j < 32; ++j) {
    const int2 cm = colm[j];
    const int kj = kt * 32 + j;
    u32 m = 0;
    if (kj < q) m = 1u + (rs == cm.x ? 1u : 0u) + (((rb & (u32)cm.y) != 0u) ? 1u : 0u);
    w |= (u64)m << (2 * j);
  }
  maskw[((size_t)b * 32 + kt) * 1024 + q] = w;
}

// ---------- GEMM: C[m][n] = (sum_k A[m][k]*W[n][k] + bias[n]) * scale ----------
// CASTA=1: A is f32, reg-staged + converted to bf16 LDS. CASTA=0: A bf16 via gload_lds.
// W: bf16 [N][K]. MODE 0: bf16 [b][h][s][64]; MODE 1: bf16 [b][h][64][1024] (V^T);
// MODE 2: f32 row-major [M][N]
template <int MODE, int CASTA>
__global__ __launch_bounds__(256) void gemm_bt(const void* __restrict__ Ap,
                                               const u16* __restrict__ W,
                                               const float* __restrict__ bias,
                                               void* __restrict__ outp,
                                               int M, int N, int K, float scale) {
  __shared__ __align__(16) u16 As[128 * 64];
  __shared__ __align__(16) u16 Bs[128 * 64];
  const int t    = threadIdx.x;
  const int lane = t & 63;
  const int wid  = t >> 6;
  const int g    = lane >> 4, l15 = lane & 15;
  const int wm   = wid >> 1, wn = wid & 1;
  const int nb   = N >> 7;
  const int mb   = blockIdx.x / nb, nbi = blockIdx.x % nb;
  const int m0   = mb << 7, n0 = nbi << 7;
  const int srow = t >> 3;
  const int scol = (t & 7) << 3;

  f32x4 acc[4][4];
#pragma unroll
  for (int i = 0; i < 4; ++i)
#pragma unroll
    for (int j = 0; j < 4; ++j) acc[i][j] = f32x4{0.f, 0.f, 0.f, 0.f};

  for (int k0 = 0; k0 < K; k0 += 64) {
    __syncthreads();
#pragma unroll
    for (int i = 0; i < 4; ++i) {
      const u16* sb = W + (size_t)(n0 + i * 32 + srow) * K + k0 + scol;
      gload_lds16(sb, Bs + i * 2048 + t * 8);
    }
    if (CASTA) {
      const float* Af = (const float*)Ap;
#pragma unroll
      for (int i = 0; i < 4; ++i) {
        const float* src = Af + (size_t)(m0 + 32 * i + (t >> 3)) * K + k0 + ((t & 7) << 3);
        const float4 x = *(const float4*)src;
        const float4 y = *(const float4*)(src + 4);
        u32x4 r;
        r.x = cvtpk(x.x, x.y); r.y = cvtpk(x.z, x.w);
        r.z = cvtpk(y.x, y.y); r.w = cvtpk(y.z, y.w);
        *(u32x4*)(As + (32 * i + (t >> 3)) * 64 + ((t & 7) << 3)) = r;
      }
    } else {
      const u16* Ab = (const u16*)Ap;
#pragma unroll
      for (int i = 0; i < 4; ++i) {
        const u16* sa = Ab + (size_t)(m0 + i * 32 + srow) * K + k0 + scol;
        gload_lds16(sa, As + i * 2048 + t * 8);
      }
    }
    __syncthreads();
#pragma unroll
    for (int kk = 0; kk < 2; ++kk) {
      short8 a[4], b[4];
#pragma unroll
      for (int mi = 0; mi < 4; ++mi)
        a[mi] = *(const short8*)(As + (wm * 64 + mi * 16 + l15) * 64 + kk * 32 + g * 8);
#pragma unroll
      for (int ni = 0; ni < 4; ++ni)
        b[ni] = *(const short8*)(Bs + (wn * 64 + ni * 16 + l15) * 64 + kk * 32 + g * 8);
#pragma unroll
      for (int mi = 0; mi < 4; ++mi)
#pragma unroll
        for (int ni = 0; ni < 4; ++ni)
          acc[mi][ni] = __builtin_amdgcn_mfma_f32_16x16x32_bf16(a[mi], b[ni], acc[mi][ni], 0, 0, 0);
    }
  }

#pragma unroll
  for (int ni = 0; ni < 4; ++ni) {
    const int col = n0 + wn * 64 + ni * 16 + l15;
    const float bz = bias[col];
#pragma unroll
    for (int mi = 0; mi < 4; ++mi) {
#pragma unroll
      for (int r = 0; r < 4; ++r) {
        const int row = m0 + wm * 64 + mi * 16 + g * 4 + r;
        const float val = (acc[mi][ni][r] + bz) * scale;
        if (MODE == 2) {
          ((float*)outp)[(size_t)row * N + col] = val;
        } else if (MODE == 0) {
          const size_t ad = ((size_t)(row >> 10) * 8 + (col >> 6)) * 65536
                          + (size_t)(row & 1023) * 64 + (col & 63);
          ((u16*)outp)[ad] = f2bf(val);
        } else {
          const size_t ad = ((size_t)(row >> 10) * 8 + (col >> 6)) * 65536
                          + (size_t)(col & 63) * 1024 + (row & 1023);
          ((u16*)outp)[ad] = f2bf(val);
        }
      }
    }
  }
}

// ---------- flash attention, swapped-QK 32x32, precomputed 2-bit mask ----------
// KVBLK=32. Softmax per element: bfe+cmp+cndmask+add+ldexp (adj = 2^(m-2) folded
// as ldexp(p,m) with epilogue inv = 0.25/l). K-frags + mask word prefetched one
// tile ahead; V-frags issued right after QK. grid (h, qb, b), wave jt = wid*8+qb.
__global__ __launch_bounds__(256, 4) void attn_kernel(const u16* __restrict__ qh,
                                                      const u16* __restrict__ kh,
                                                      const u16* __restrict__ vT,
                                                      const u64* __restrict__ maskw,
                                                      u16* __restrict__ outc) {
  const int h  = blockIdx.x;
  const int qb = blockIdx.y;
  const int b  = blockIdx.z;
  const int lane = threadIdx.x & 63;
  const int wid  = threadIdx.x >> 6;
  const int l31 = lane & 31;
  const int hh  = lane >> 5;
  const int hh8 = hh << 3, fourh = hh << 2, eighth = hh << 3;
  const int jt = wid * 8 + qb;            // q-tile 0..31
  const int q0 = jt << 5;
  const int qi = q0 + l31;
  const size_t bh = (size_t)b * 8 + h;
  const u16* Q  = qh + bh * 65536;
  const u16* Kp = kh + bh * 65536;
  const u16* Vt = vT + bh * 65536;
  const u64* mrow = maskw + (size_t)b * 32 * 1024 + qi;   // stride 1024 per ktile

  __shared__ __align__(16) float Sl[4][32];

  short8 qB[4];
#pragma unroll
  for (int i = 0; i < 4; ++i)
    qB[i] = *(const short8*)(Q + (size_t)qi * 64 + i * 16 + eighth);

  f32x16 O0, O1;
#pragma unroll
  for (int i = 0; i < 16; ++i) { O0[i] = 0.f; O1[i] = 0.f; }
  float lrun = 0.f;

  const int nt = jt + 1;

  short8 kA[4];
#pragma unroll
  for (int i = 0; i < 4; ++i)
    kA[i] = *(const short8*)(Kp + (size_t)l31 * 64 + i * 16 + eighth);
  u64 wm = mrow[0];

  for (int t = 0; t < nt; ++t) {
    const int k0 = t << 5;

    // S' = K Q^T (32 k-rows, chained over d=64)
    f32x16 S;
#pragma unroll
    for (int i = 0; i < 16; ++i) S[i] = 0.f;
#pragma unroll
    for (int i = 0; i < 4; ++i)
      S = __builtin_amdgcn_mfma_f32_32x32x16_bf16(kA[i], qB[i], S, 0, 0, 0);

    // prefetch next K tile + next mask word (consumed next iteration)
    u64 wmn = 0;
    if (t + 1 < nt) {
#pragma unroll
      for (int i = 0; i < 4; ++i)
        kA[i] = *(const short8*)(Kp + (size_t)(k0 + 32 + l31) * 64 + i * 16 + eighth);
      wmn = mrow[(size_t)(t + 1) << 10];
    }

    // V B-frags for THIS tile, issued before softmax (latency hidden under it)
    short8 vB[2][2];
#pragma unroll
    for (int t4 = 0; t4 < 2; ++t4) {
      vB[t4][0] = *(const short8*)(Vt + (size_t)l31 * 1024 + k0 + t4 * 16 + eighth);
      vB[t4][1] = *(const short8*)(Vt + (size_t)(32 + l31) * 1024 + k0 + t4 * 16 + eighth);
    }

    // softmax: p = 2^s, m2 = 2-bit mask, padj = ldexp(p, m2) (= 4 * p*2^(m2-2))
    const u32 wsh0 = ((u32)wm) >> hh8;
    const u32 wsh1 = ((u32)(wm >> 32)) >> hh8;
    u32 pk[8];
#pragma unroll
    for (int s = 0; s < 4; ++s) {
      const u32 wsel = (s < 2) ? wsh0 : wsh1;
      float pv[4];
#pragma unroll
      for (int r = 0; r < 4; ++r) {
        const int m = 4 * s + r;
        const u32 m2 = (wsel >> (2 * r + 16 * (s & 1))) & 3u;
        float e;
        asm("v_exp_f32 %0, %1" : "=v"(e) : "v"(S[m]));
        const float p = (m2 != 0u) ? e : 0.f;
        lrun += p;
        asm("v_ldexp_f32 %0, %1, %2" : "=v"(pv[r]) : "v"(p), "v"(m2));
      }
      pk[2 * s]     = cvtpk(pv[0], pv[1]);
      pk[2 * s + 1] = cvtpk(pv[2], pv[3]);
    }
    wm = wmn;

    // PV: redistribute P via permlane32_swap, 2 chunks of 16 k
#pragma unroll
    for (int t4 = 0; t4 < 2; ++t4) {
      u32 a0 = pk[4 * t4 + 0], b0 = pk[4 * t4 + 2];
      u32 a1 = pk[4 * t4 + 1], b1 = pk[4 * t4 + 3];
      asm("v_permlane32_swap_b32 %0, %1" : "+v"(a0), "+v"(b0));
      asm("v_permlane32_swap_b32 %0, %1" : "+v"(a1), "+v"(b1));
      u32x4 w; w.x = a0; w.y = a1; w.z = b0; w.w = b1;
      const short8 pa = __builtin_bit_cast(short8, w);
      O0 = __builtin_amdgcn_mfma_f32_32x32x16_bf16(pa, vB[t4][0], O0, 0, 0, 0);
      O1 = __builtin_amdgcn_mfma_f32_32x32x16_bf16(pa, vB[t4][1], O1, 0, 0, 0);
    }
  }

  // epilogue: row-sum of l, inv = 0.25/l (ldexp(p,m) = 4x adjusted), write bf16
  const float ssum = lrun + __shfl_xor(lrun, 32);
  if (lane < 32) Sl[wid][l31] = (ssum > 0.f) ? 0.25f / ssum : 0.f;
  __builtin_amdgcn_sched_barrier(0);
  asm volatile("s_waitcnt lgkmcnt(0)" ::: "memory");
  __builtin_amdgcn_sched_barrier(0);
#pragma unroll
  for (int t2 = 0; t2 < 4; ++t2) {
    const float4 inv4 = *(const float4*)&Sl[wid][8 * t2 + fourh];
#pragma unroll
    for (int r = 0; r < 4; ++r) {
      const int m = 4 * t2 + r;
      const float iv = (r == 0) ? inv4.x : (r == 1) ? inv4.y : (r == 2) ? inv4.z : inv4.w;
      const int qrow = q0 + 8 * t2 + fourh + r;
      u16* op = outc + ((size_t)b * 1024 + qrow) * 512 + h * 64;
      op[l31]      = f2bf(O0[m] * iv);
      op[32 + l31] = f2bf(O1[m] * iv);
    }
  }
}

// ---------- launch ----------
extern "C" void kernel_launch(void* const* d_in, const int* in_sizes, int n_in,
                              void* d_out, int out_size, void* d_ws, size_t ws_size,
                              hipStream_t stream) {
  (void)in_sizes; (void)n_in; (void)out_size; (void)ws_size;
  const float* q    = (const float*)d_in[0];
  const float* k    = (const float*)d_in[1];
  const float* v    = (const float*)d_in[2];
  const int*  q_seq = (const int*)d_in[3];
  const int*  c_seq = (const int*)d_in[4];
  const float* Wq   = (const float*)d_in[5];
  const float* bq   = (const float*)d_in[6];
  const float* Wk   = (const float*)d_in[7];
  const float* bk   = (const float*)d_in[8];
  const float* Wv   = (const float*)d_in[9];
  const float* bv   = (const float*)d_in[10];
  const float* Wo   = (const float*)d_in[11];
  const float* bo   = (const float*)d_in[12];
  float* out = (float*)d_out;

  char* ws = (char*)d_ws;
  const size_t SZH = 16ull * 8 * 1024 * 64 * 2;   // 16.78 MB per [B][H][S][64] bf16
  u16* qhb   = (u16*)(ws + 0 * SZH);
  u16* khb   = (u16*)(ws + 1 * SZH);
  u16* vTb   = (u16*)(ws + 2 * SZH);
  u16* attnc = (u16*)(ws + 3 * SZH);
  u16* Wvb = (u16*)(ws + 4 * SZH + 0 * 524288);
  u16* Wkb = (u16*)(ws + 4 * SZH + 1 * 524288);
  u16* Wqb = (u16*)(ws + 4 * SZH + 2 * 524288);
  u16* Wob = (u16*)(ws + 4 * SZH + 3 * 524288);
  int2* meta  = (int2*)(ws + 4 * SZH + 4 * 524288);
  u64* maskw  = (u64*)(ws + 4 * SZH + 4 * 524288 + 131072);

  const int n8w = 512 * 512 / 8;
  cast_kernel<<<n8w / 256, 256, 0, stream>>>(Wv, Wvb, n8w);
  cast_kernel<<<n8w / 256, 256, 0, stream>>>(Wk, Wkb, n8w);
  cast_kernel<<<n8w / 256, 256, 0, stream>>>(Wq, Wqb, n8w);
  cast_kernel<<<n8w / 256, 256, 0, stream>>>(Wo, Wob, n8w);
  pack_kernel<<<64, 256, 0, stream>>>(q_seq, c_seq, meta, 16384);
  mask_kernel<<<dim3(4, 32, 16), 256, 0, stream>>>(meta, maskw);

  const int M = 16384, N = 512, K = 512;
  dim3 gg(512);
  const float KSCALE = 0.18033688011112042f;   // log2(e)/8 -> softmax exp is 2^s
  // NB reference's weight shuffle: qh uses Wv/bv, kh uses Wk/bk, vh uses Wq/bq
  gemm_bt<0, 1><<<gg, 256, 0, stream>>>(q, Wvb, bv, qhb, M, N, K, 1.0f);
  gemm_bt<0, 1><<<gg, 256, 0, stream>>>(k, Wkb, bk, khb, M, N, K, KSCALE);
  gemm_bt<1, 1><<<gg, 256, 0, stream>>>(v, Wqb, bq, vTb, M, N, K, 1.0f);
  attn_kernel<<<dim3(8, 8, 16), 256, 0, stream>>>(qhb, khb, vTb, maskw, attnc);
  gemm_bt<2, 0><<<gg, 256, 0, stream>>>(attnc, Wob, bo, out, M, N, K, 1.0f);
}

// Round 5
// 170.040 us; speedup vs baseline: 1.9254x; 1.1786x over previous
//
#include <hip/hip_runtime.h>
#include <stdint.h>

typedef unsigned short u16;
typedef unsigned int   u32;
typedef unsigned long long u64;
typedef __attribute__((ext_vector_type(8)))  short short8;   // 8 x bf16 fragment
typedef __attribute__((ext_vector_type(4)))  float f32x4;
typedef __attribute__((ext_vector_type(16))) float f32x16;   // 32x32 MFMA accumulator
typedef __attribute__((ext_vector_type(4)))  unsigned int u32x4;

// ---------- helpers ----------
__device__ __forceinline__ u16 f2bf(float f) {          // RNE f32 -> bf16
  u32 u = __builtin_bit_cast(u32, f);
  u32 r = u + 0x7FFFu + ((u >> 16) & 1u);
  return (u16)(r >> 16);
}

__device__ __forceinline__ u32 cvtpk(float a, float b) { // 2xf32 -> packed bf16
  u32 r;
  asm("v_cvt_pk_bf16_f32 %0, %1, %2" : "=v"(r) : "v"(a), "v"(b));
  return r;
}

// async global->LDS, 16B per lane (dest must be wave-uniform base + lane*16)
__device__ __forceinline__ void gload_lds16(const void* g, void* l) {
  __builtin_amdgcn_global_load_lds(
      (__attribute__((address_space(1))) void*)(uintptr_t)g,
      (__attribute__((address_space(3))) void*)(u32)(uintptr_t)l,
      16, 0, 0);
}

// ---------- fused weight casts: grid.y selects which 512x512 matrix ----------
__global__ void cast4_kernel(const float* __restrict__ s0, const float* __restrict__ s1,
                             const float* __restrict__ s2, const float* __restrict__ s3,
                             u16* __restrict__ d0, u16* __restrict__ d1,
                             u16* __restrict__ d2, u16* __restrict__ d3, int n8) {
  const int sel = blockIdx.y;
  const float* src = sel == 0 ? s0 : sel == 1 ? s1 : sel == 2 ? s2 : s3;
  u16* dst = sel == 0 ? d0 : sel == 1 ? d1 : sel == 2 ? d2 : d3;
  int i = blockIdx.x * blockDim.x + threadIdx.x;
  if (i >= n8) return;
  const float4* s4 = (const float4*)src;
  float4 x = s4[2 * (size_t)i];
  float4 y = s4[2 * (size_t)i + 1];
  u32x4 r;
  r.x = cvtpk(x.x, x.y); r.y = cvtpk(x.z, x.w);
  r.z = cvtpk(y.x, y.y); r.w = cvtpk(y.z, y.w);
  *(u32x4*)(dst + 8 * (size_t)i) = r;
}

// ---------- pack {q_seq, c_bits} per position ----------
__global__ void pack_kernel(const int* __restrict__ q_seq, const int* __restrict__ c_seq,
                            int2* __restrict__ meta, int n) {
  int i = blockIdx.x * blockDim.x + threadIdx.x;
  if (i >= n) return;
  u32 bits = 0;
#pragma unroll
  for (int j = 0; j < 32; ++j)
    bits |= (c_seq[(size_t)i * 32 + j] != 0) ? (1u << j) : 0u;
  meta[i] = make_int2(q_seq[i], (int)bits);
}

// ---------- mask precompute: 2-bit m per (b, ktile32, q), tri included ----------
__global__ __launch_bounds__(256) void mask_kernel(const int2* __restrict__ meta,
                                                   u64* __restrict__ maskw) {
  const int qc = blockIdx.x, kt = blockIdx.y, b = blockIdx.z;
  const int t = threadIdx.x;
  const int q = qc * 256 + t;
  __shared__ int2 colm[32];
  if (t < 32) colm[t] = meta[b * 1024 + kt * 32 + t];
  __syncthreads();
  const int2 qm = meta[b * 1024 + q];
  const int rs = qm.x; const u32 rb = (u32)qm.y;
  u64 w = 0;
#pragma unroll
  for (int j = 0; j < 32; ++j) {
    const int2 cm = colm[j];
    const int kj = kt * 32 + j;
    u32 m = 0;
    if (kj < q) m = 1u + (rs == cm.x ? 1u : 0u) + (((rb & (u32)cm.y) != 0u) ? 1u : 0u);
    w |= (u64)m << (2 * j);
  }
  maskw[((size_t)b * 32 + kt) * 1024 + q] = w;
}

// ---------- fused QKV projection GEMM (grid.y = sel: 0->qh, 1->kh, 2->vT) ----
// A f32 reg-staged->bf16 LDS; W bf16 via gload_lds. Layouts:
//  sel 0 (Q): [b][h][s][64]
//  sel 1 (K): tiled [b][h][s/32][d/8][s&31][d&7]  (attn reads 1KB contig)
//  sel 2 (V): tiled [b][h][s/8][d][s&7]           (attn reads 2x512B contig)
__global__ __launch_bounds__(256) void gemm_qkv(const float* __restrict__ qf,
                                                const float* __restrict__ kf,
                                                const float* __restrict__ vf,
                                                const u16* __restrict__ Wvb,
                                                const u16* __restrict__ Wkb,
                                                const u16* __restrict__ Wqb,
                                                const float* __restrict__ bv,
                                                const float* __restrict__ bk,
                                                const float* __restrict__ bq,
                                                u16* __restrict__ qhb,
                                                u16* __restrict__ khb,
                                                u16* __restrict__ vTb,
                                                float kscale) {
  const int sel = blockIdx.y;
  const float* Af   = sel == 0 ? qf : sel == 1 ? kf : vf;
  const u16*   W    = sel == 0 ? Wvb : sel == 1 ? Wkb : Wqb;   // ref weight shuffle
  const float* bias = sel == 0 ? bv : sel == 1 ? bk : bq;
  const float scale = sel == 1 ? kscale : 1.0f;
  const int K = 512, N = 512;

  __shared__ __align__(16) u16 As[128 * 64];
  __shared__ __align__(16) u16 Bs[128 * 64];
  const int t    = threadIdx.x;
  const int lane = t & 63;
  const int wid  = t >> 6;
  const int g    = lane >> 4, l15 = lane & 15;
  const int wm   = wid >> 1, wn = wid & 1;
  const int mb   = blockIdx.x >> 2, nbi = blockIdx.x & 3;
  const int m0   = mb << 7, n0 = nbi << 7;
  const int srow = t >> 3;
  const int scol = (t & 7) << 3;

  f32x4 acc[4][4];
#pragma unroll
  for (int i = 0; i < 4; ++i)
#pragma unroll
    for (int j = 0; j < 4; ++j) acc[i][j] = f32x4{0.f, 0.f, 0.f, 0.f};

  for (int k0 = 0; k0 < K; k0 += 64) {
    __syncthreads();
#pragma unroll
    for (int i = 0; i < 4; ++i) {
      const u16* sb = W + (size_t)(n0 + i * 32 + srow) * K + k0 + scol;
      gload_lds16(sb, Bs + i * 2048 + t * 8);
    }
#pragma unroll
    for (int i = 0; i < 4; ++i) {
      const float* src = Af + (size_t)(m0 + 32 * i + srow) * K + k0 + scol;
      const float4 x = *(const float4*)src;
      const float4 y = *(const float4*)(src + 4);
      u32x4 r;
      r.x = cvtpk(x.x, x.y); r.y = cvtpk(x.z, x.w);
      r.z = cvtpk(y.x, y.y); r.w = cvtpk(y.z, y.w);
      *(u32x4*)(As + (32 * i + srow) * 64 + scol) = r;
    }
    __syncthreads();
#pragma unroll
    for (int kk = 0; kk < 2; ++kk) {
      short8 a[4], b[4];
#pragma unroll
      for (int mi = 0; mi < 4; ++mi)
        a[mi] = *(const short8*)(As + (wm * 64 + mi * 16 + l15) * 64 + kk * 32 + g * 8);
#pragma unroll
      for (int ni = 0; ni < 4; ++ni)
        b[ni] = *(const short8*)(Bs + (wn * 64 + ni * 16 + l15) * 64 + kk * 32 + g * 8);
#pragma unroll
      for (int mi = 0; mi < 4; ++mi)
#pragma unroll
        for (int ni = 0; ni < 4; ++ni)
          acc[mi][ni] = __builtin_amdgcn_mfma_f32_16x16x32_bf16(a[mi], b[ni], acc[mi][ni], 0, 0, 0);
    }
  }

#pragma unroll
  for (int ni = 0; ni < 4; ++ni) {
    const int col = n0 + wn * 64 + ni * 16 + l15;
    const float bz = bias[col];
#pragma unroll
    for (int mi = 0; mi < 4; ++mi) {
#pragma unroll
      for (int r = 0; r < 4; ++r) {
        const int row = m0 + wm * 64 + mi * 16 + g * 4 + r;
        const u16 val = f2bf((acc[mi][ni][r] + bz) * scale);
        const size_t base = ((size_t)(row >> 10) * 8 + (col >> 6)) * 65536;
        const int s = row & 1023, d = col & 63;
        if (sel == 0) {
          qhb[base + (size_t)s * 64 + d] = val;
        } else if (sel == 1) {
          khb[base + (s >> 5) * 2048 + (d >> 3) * 256 + (s & 31) * 8 + (d & 7)] = val;
        } else {
          vTb[base + (s >> 3) * 512 + d * 8 + (s & 7)] = val;
        }
      }
    }
  }
}

// ---------- final GEMM: out = attnc @ Wo^T + bo (f32 out) ----------
__global__ __launch_bounds__(256) void gemm_out(const u16* __restrict__ A,
                                                const u16* __restrict__ W,
                                                const float* __restrict__ bias,
                                                float* __restrict__ outp) {
  const int K = 512, N = 512;
  __shared__ __align__(16) u16 As[128 * 64];
  __shared__ __align__(16) u16 Bs[128 * 64];
  const int t    = threadIdx.x;
  const int lane = t & 63;
  const int wid  = t >> 6;
  const int g    = lane >> 4, l15 = lane & 15;
  const int wm   = wid >> 1, wn = wid & 1;
  const int mb   = blockIdx.x >> 2, nbi = blockIdx.x & 3;
  const int m0   = mb << 7, n0 = nbi << 7;
  const int srow = t >> 3;
  const int scol = (t & 7) << 3;

  f32x4 acc[4][4];
#pragma unroll
  for (int i = 0; i < 4; ++i)
#pragma unroll
    for (int j = 0; j < 4; ++j) acc[i][j] = f32x4{0.f, 0.f, 0.f, 0.f};

  for (int k0 = 0; k0 < K; k0 += 64) {
    __syncthreads();
#pragma unroll
    for (int i = 0; i < 4; ++i) {
      const u16* sa = A + (size_t)(m0 + i * 32 + srow) * K + k0 + scol;
      const u16* sb = W + (size_t)(n0 + i * 32 + srow) * K + k0 + scol;
      gload_lds16(sa, As + i * 2048 + t * 8);
      gload_lds16(sb, Bs + i * 2048 + t * 8);
    }
    __syncthreads();
#pragma unroll
    for (int kk = 0; kk < 2; ++kk) {
      short8 a[4], b[4];
#pragma unroll
      for (int mi = 0; mi < 4; ++mi)
        a[mi] = *(const short8*)(As + (wm * 64 + mi * 16 + l15) * 64 + kk * 32 + g * 8);
#pragma unroll
      for (int ni = 0; ni < 4; ++ni)
        b[ni] = *(const short8*)(Bs + (wn * 64 + ni * 16 + l15) * 64 + kk * 32 + g * 8);
#pragma unroll
      for (int mi = 0; mi < 4; ++mi)
#pragma unroll
        for (int ni = 0; ni < 4; ++ni)
          acc[mi][ni] = __builtin_amdgcn_mfma_f32_16x16x32_bf16(a[mi], b[ni], acc[mi][ni], 0, 0, 0);
    }
  }

#pragma unroll
  for (int ni = 0; ni < 4; ++ni) {
    const int col = n0 + wn * 64 + ni * 16 + l15;
    const float bz = bias[col];
#pragma unroll
    for (int mi = 0; mi < 4; ++mi)
#pragma unroll
      for (int r = 0; r < 4; ++r) {
        const int row = m0 + wm * 64 + mi * 16 + g * 4 + r;
        outp[(size_t)row * N + col] = acc[mi][ni][r] + bz;
      }
  }
}

// ---------- flash attention: wave-pair kv-split, swapped-QK 32x32 ----------
// Pair (2 waves) owns one 32-row q-tile; wave p takes kv tiles t=p,p+2,...
// (plain-sum softmax => partial O/l just add; merged via LDS). Block pairs
// jt={qp, 31-qp} => every block exactly 33 tiles. K tiled (1KB contig loads),
// V tiled (2x512B). Softmax: p=2^s, padj=ldexp(p,m2), inv=0.25/l.
__global__ __launch_bounds__(256, 4) void attn_kernel(const u16* __restrict__ qh,
                                                      const u16* __restrict__ kh,
                                                      const u16* __restrict__ vT,
                                                      const u64* __restrict__ maskw,
                                                      u16* __restrict__ outc) {
  const int h  = blockIdx.x;
  const int qp = blockIdx.y;
  const int b  = blockIdx.z;
  const int lane = threadIdx.x & 63;
  const int wid  = threadIdx.x >> 6;
  const int pair = wid >> 1, p = wid & 1;
  const int l31 = lane & 31;
  const int hh  = lane >> 5;
  const int hh8 = hh << 3, fourh = hh << 2, eighth = hh << 3;
  const int jt = pair ? (31 - qp) : qp;   // q-tile index 0..31
  const int q0 = jt << 5;
  const int qi = q0 + l31;
  const size_t bh = (size_t)b * 8 + h;
  const u16* Q  = qh + bh * 65536;
  const u16* Kp = kh + bh * 65536;
  const u16* Vt = vT + bh * 65536;
  const u64* mrow = maskw + (size_t)b * 32768 + qi;

  __shared__ float mO[2][32][64];
  __shared__ float mL[2][64];
  __shared__ __align__(16) float Sl[2][32];

  short8 qB[4];
#pragma unroll
  for (int i = 0; i < 4; ++i)
    qB[i] = *(const short8*)(Q + (size_t)qi * 64 + i * 16 + eighth);

  f32x16 O0, O1;
#pragma unroll
  for (int i = 0; i < 16; ++i) { O0[i] = 0.f; O1[i] = 0.f; }
  float lr[4] = {0.f, 0.f, 0.f, 0.f};

  const int nt = jt + 1;

  // prologue: tile t=p (always in-bounds memory even if p >= nt)
  short8 kA[4];
#pragma unroll
  for (int i = 0; i < 4; ++i)
    kA[i] = *(const short8*)(Kp + p * 2048 + ((2 * i + hh) * 32 + l31) * 8);
  u64 wm = mrow[(size_t)p << 10];

  for (int t = p; t < nt; t += 2) {
    const int k0 = t << 5;

    // S' = K Q^T
    f32x16 S;
#pragma unroll
    for (int i = 0; i < 16; ++i) S[i] = 0.f;
#pragma unroll
    for (int i = 0; i < 4; ++i)
      S = __builtin_amdgcn_mfma_f32_32x32x16_bf16(kA[i], qB[i], S, 0, 0, 0);

    // prefetch tile t+2 (this wave's next)
    u64 wmn = 0;
    if (t + 2 < nt) {
#pragma unroll
      for (int i = 0; i < 4; ++i)
        kA[i] = *(const short8*)(Kp + (t + 2) * 2048 + ((2 * i + hh) * 32 + l31) * 8);
      wmn = mrow[(size_t)(t + 2) << 10];
    }

    // V B-frags for THIS tile (issued before softmax, latency hidden)
    short8 vB[2][2];
#pragma unroll
    for (int t4 = 0; t4 < 2; ++t4)
#pragma unroll
      for (int j = 0; j < 2; ++j)
        vB[t4][j] = *(const short8*)(Vt + (size_t)(t * 4 + t4 * 2 + hh) * 512 + (32 * j + l31) * 8);

    // softmax: p = 2^s, m2 = 2-bit mask, padj = ldexp(p, m2)
    const u32 wsh0 = ((u32)wm) >> hh8;
    const u32 wsh1 = ((u32)(wm >> 32)) >> hh8;
    u32 pk[8];
#pragma unroll
    for (int s = 0; s < 4; ++s) {
      const u32 wsel = (s < 2) ? wsh0 : wsh1;
      float pv[4];
#pragma unroll
      for (int r = 0; r < 4; ++r) {
        const int m = 4 * s + r;
        const u32 m2 = (wsel >> (2 * r + 16 * (s & 1))) & 3u;
        float e;
        asm("v_exp_f32 %0, %1" : "=v"(e) : "v"(S[m]));
        const float pp = (m2 != 0u) ? e : 0.f;
        lr[r] += pp;
        asm("v_ldexp_f32 %0, %1, %2" : "=v"(pv[r]) : "v"(pp), "v"(m2));
      }
      pk[2 * s]     = cvtpk(pv[0], pv[1]);
      pk[2 * s + 1] = cvtpk(pv[2], pv[3]);
    }
    wm = wmn;

    // PV via permlane32_swap
#pragma unroll
    for (int t4 = 0; t4 < 2; ++t4) {
      u32 a0 = pk[4 * t4 + 0], b0 = pk[4 * t4 + 2];
      u32 a1 = pk[4 * t4 + 1], b1 = pk[4 * t4 + 3];
      asm("v_permlane32_swap_b32 %0, %1" : "+v"(a0), "+v"(b0));
      asm("v_permlane32_swap_b32 %0, %1" : "+v"(a1), "+v"(b1));
      u32x4 w; w.x = a0; w.y = a1; w.z = b0; w.w = b1;
      const short8 pa = __builtin_bit_cast(short8, w);
      O0 = __builtin_amdgcn_mfma_f32_32x32x16_bf16(pa, vB[t4][0], O0, 0, 0, 0);
      O1 = __builtin_amdgcn_mfma_f32_32x32x16_bf16(pa, vB[t4][1], O1, 0, 0, 0);
    }
  }

  float lrun = (lr[0] + lr[1]) + (lr[2] + lr[3]);

  // pair merge: odd wave publishes partials, even wave combines + writes
  if (p == 1) {
#pragma unroll
    for (int r = 0; r < 16; ++r) {
      mO[pair][r][lane]      = O0[r];
      mO[pair][16 + r][lane] = O1[r];
    }
    mL[pair][lane] = lrun;
  }
  __syncthreads();
  if (p == 0) {
#pragma unroll
    for (int r = 0; r < 16; ++r) {
      O0[r] += mO[pair][r][lane];
      O1[r] += mO[pair][16 + r][lane];
    }
    lrun += mL[pair][lane];

    const float ssum = lrun + __shfl_xor(lrun, 32);
    if (lane < 32) Sl[pair][l31] = (ssum > 0.f) ? 0.25f / ssum : 0.f;
    __builtin_amdgcn_sched_barrier(0);
    asm volatile("s_waitcnt lgkmcnt(0)" ::: "memory");
    __builtin_amdgcn_sched_barrier(0);
#pragma unroll
    for (int t2 = 0; t2 < 4; ++t2) {
      const float4 inv4 = *(const float4*)&Sl[pair][8 * t2 + fourh];
#pragma unroll
      for (int r = 0; r < 4; ++r) {
        const int m = 4 * t2 + r;
        const float iv = (r == 0) ? inv4.x : (r == 1) ? inv4.y : (r == 2) ? inv4.z : inv4.w;
        const int qrow = q0 + 8 * t2 + fourh + r;
        u16* op = outc + ((size_t)b * 1024 + qrow) * 512 + h * 64;
        op[l31]      = f2bf(O0[m] * iv);
        op[32 + l31] = f2bf(O1[m] * iv);
      }
    }
  }
}

// ---------- launch ----------
extern "C" void kernel_launch(void* const* d_in, const int* in_sizes, int n_in,
                              void* d_out, int out_size, void* d_ws, size_t ws_size,
                              hipStream_t stream) {
  (void)in_sizes; (void)n_in; (void)out_size; (void)ws_size;
  const float* q    = (const float*)d_in[0];
  const float* k    = (const float*)d_in[1];
  const float* v    = (const float*)d_in[2];
  const int*  q_seq = (const int*)d_in[3];
  const int*  c_seq = (const int*)d_in[4];
  const float* Wq   = (const float*)d_in[5];
  const float* bq   = (const float*)d_in[6];
  const float* Wk   = (const float*)d_in[7];
  const float* bk   = (const float*)d_in[8];
  const float* Wv   = (const float*)d_in[9];
  const float* bv   = (const float*)d_in[10];
  const float* Wo   = (const float*)d_in[11];
  const float* bo   = (const float*)d_in[12];
  float* out = (float*)d_out;

  char* ws = (char*)d_ws;
  const size_t SZH = 16ull * 8 * 1024 * 64 * 2;   // 16.78 MB per [B][H][...] bf16
  u16* qhb   = (u16*)(ws + 0 * SZH);
  u16* khb   = (u16*)(ws + 1 * SZH);
  u16* vTb   = (u16*)(ws + 2 * SZH);
  u16* attnc = (u16*)(ws + 3 * SZH);
  u16* Wvb = (u16*)(ws + 4 * SZH + 0 * 524288);
  u16* Wkb = (u16*)(ws + 4 * SZH + 1 * 524288);
  u16* Wqb = (u16*)(ws + 4 * SZH + 2 * 524288);
  u16* Wob = (u16*)(ws + 4 * SZH + 3 * 524288);
  int2* meta  = (int2*)(ws + 4 * SZH + 4 * 524288);
  u64* maskw  = (u64*)(ws + 4 * SZH + 4 * 524288 + 131072);

  const int n8w = 512 * 512 / 8;
  cast4_kernel<<<dim3(n8w / 256, 4), 256, 0, stream>>>(Wv, Wk, Wq, Wo,
                                                       Wvb, Wkb, Wqb, Wob, n8w);
  pack_kernel<<<64, 256, 0, stream>>>(q_seq, c_seq, meta, 16384);
  mask_kernel<<<dim3(4, 32, 16), 256, 0, stream>>>(meta, maskw);

  const float KSCALE = 0.18033688011112042f;   // log2(e)/8 -> softmax exp is 2^s
  gemm_qkv<<<dim3(512, 3), 256, 0, stream>>>(q, k, v, Wvb, Wkb, Wqb,
                                             bv, bk, bq, qhb, khb, vTb, KSCALE);
  attn_kernel<<<dim3(8, 16, 16), 256, 0, stream>>>(qhb, khb, vTb, maskw, attnc);
  gemm_out<<<512, 256, 0, stream>>>(attnc, Wob, bo, out);
}

// Round 6
// 142.560 us; speedup vs baseline: 2.2965x; 1.1928x over previous
//
#include <hip/hip_runtime.h>
#include <stdint.h>

typedef unsigned short u16;
typedef unsigned int   u32;
typedef unsigned long long u64;
typedef __attribute__((ext_vector_type(8)))  short short8;   // 8 x bf16 fragment
typedef __attribute__((ext_vector_type(4)))  float f32x4;
typedef __attribute__((ext_vector_type(16))) float f32x16;   // 32x32 MFMA accumulator
typedef __attribute__((ext_vector_type(4)))  unsigned int u32x4;

// ---------- helpers ----------
__device__ __forceinline__ u16 f2bf(float f) {          // RNE f32 -> bf16
  u32 u = __builtin_bit_cast(u32, f);
  u32 r = u + 0x7FFFu + ((u >> 16) & 1u);
  return (u16)(r >> 16);
}

__device__ __forceinline__ u32 cvtpk(float a, float b) { // 2xf32 -> packed bf16
  u32 r;
  asm("v_cvt_pk_bf16_f32 %0, %1, %2" : "=v"(r) : "v"(a), "v"(b));
  return r;
}

// async global->LDS, 16B per lane (dest must be wave-uniform base + lane*16)
__device__ __forceinline__ void gload_lds16(const void* g, void* l) {
  __builtin_amdgcn_global_load_lds(
      (__attribute__((address_space(1))) void*)(uintptr_t)g,
      (__attribute__((address_space(3))) void*)(u32)(uintptr_t)l,
      16, 0, 0);
}

// ---------- fused weight casts: grid.y selects which 512x512 matrix ----------
__global__ void cast4_kernel(const float* __restrict__ s0, const float* __restrict__ s1,
                             const float* __restrict__ s2, const float* __restrict__ s3,
                             u16* __restrict__ d0, u16* __restrict__ d1,
                             u16* __restrict__ d2, u16* __restrict__ d3, int n8) {
  const int sel = blockIdx.y;
  const float* src = sel == 0 ? s0 : sel == 1 ? s1 : sel == 2 ? s2 : s3;
  u16* dst = sel == 0 ? d0 : sel == 1 ? d1 : sel == 2 ? d2 : d3;
  int i = blockIdx.x * blockDim.x + threadIdx.x;
  if (i >= n8) return;
  const float4* s4 = (const float4*)src;
  float4 x = s4[2 * (size_t)i];
  float4 y = s4[2 * (size_t)i + 1];
  u32x4 r;
  r.x = cvtpk(x.x, x.y); r.y = cvtpk(x.z, x.w);
  r.z = cvtpk(y.x, y.y); r.w = cvtpk(y.z, y.w);
  *(u32x4*)(dst + 8 * (size_t)i) = r;
}

// ---------- pack {q_seq, c_bits} per position ----------
__global__ void pack_kernel(const int* __restrict__ q_seq, const int* __restrict__ c_seq,
                            int2* __restrict__ meta, int n) {
  int i = blockIdx.x * blockDim.x + threadIdx.x;
  if (i >= n) return;
  u32 bits = 0;
#pragma unroll
  for (int j = 0; j < 32; ++j)
    bits |= (c_seq[(size_t)i * 32 + j] != 0) ? (1u << j) : 0u;
  meta[i] = make_int2(q_seq[i], (int)bits);
}

// ---------- mask precompute: 2-bit m per (b, ktile32, q), tri included ----------
__global__ __launch_bounds__(256) void mask_kernel(const int2* __restrict__ meta,
                                                   u64* __restrict__ maskw) {
  const int qc = blockIdx.x, kt = blockIdx.y, b = blockIdx.z;
  const int t = threadIdx.x;
  const int q = qc * 256 + t;
  __shared__ int2 colm[32];
  if (t < 32) colm[t] = meta[b * 1024 + kt * 32 + t];
  __syncthreads();
  const int2 qm = meta[b * 1024 + q];
  const int rs = qm.x; const u32 rb = (u32)qm.y;
  u64 w = 0;
#pragma unroll
  for (int j = 0; j < 32; ++j) {
    const int2 cm = colm[j];
    const int kj = kt * 32 + j;
    u32 m = 0;
    if (kj < q) m = 1u + (rs == cm.x ? 1u : 0u) + (((rb & (u32)cm.y) != 0u) ? 1u : 0u);
    w |= (u64)m << (2 * j);
  }
  maskw[((size_t)b * 32 + kt) * 1024 + q] = w;
}

// ---------- fused QKV projection GEMM (grid.y = sel: 0->qh, 1->kh, 2->vT) ----
// T2 XOR-swizzled LDS (phys slot = logical slot ^ (row&7); applied via
// pre-swizzled SOURCE col, linear LDS dest — rule #21) + T4-lite pipeline:
// raw barriers, A f32 prefetched one K-step ahead, vmcnt(8) counted wait.
// XCD swizzle: w=(x&7)*64+(x>>3) so the 4 nbi of one mb share an XCD L2.
//  sel 0 (Q): [b][h][s][64]
//  sel 1 (K): tiled [b][h][s/32][d/8][s&31][d&7]  (attn reads 1KB contig)
//  sel 2 (V): tiled [b][h][s/8][d][s&7]           (attn reads 2x512B contig)
__global__ __launch_bounds__(256) void gemm_qkv(const float* __restrict__ qf,
                                                const float* __restrict__ kf,
                                                const float* __restrict__ vf,
                                                const u16* __restrict__ Wvb,
                                                const u16* __restrict__ Wkb,
                                                const u16* __restrict__ Wqb,
                                                const float* __restrict__ bv,
                                                const float* __restrict__ bk,
                                                const float* __restrict__ bq,
                                                u16* __restrict__ qhb,
                                                u16* __restrict__ khb,
                                                u16* __restrict__ vTb,
                                                float kscale) {
  const int sel = blockIdx.y;
  const float* Af   = sel == 0 ? qf : sel == 1 ? kf : vf;
  const u16*   W    = sel == 0 ? Wvb : sel == 1 ? Wkb : Wqb;   // ref weight shuffle
  const float* bias = sel == 0 ? bv : sel == 1 ? bk : bq;
  const float scale = sel == 1 ? kscale : 1.0f;
  const int K = 512;

  __shared__ __align__(16) u16 As[128 * 64];
  __shared__ __align__(16) u16 Bs[128 * 64];
  const int t    = threadIdx.x;
  const int lane = t & 63;
  const int wid  = t >> 6;
  const int g    = lane >> 4, l15 = lane & 15;
  const int wm   = wid >> 1, wn = wid & 1;
  const int wrk  = (blockIdx.x & 7) * 64 + (blockIdx.x >> 3);  // XCD-chunked
  const int mb   = wrk >> 2, nbi = wrk & 3;
  const int m0   = mb << 7, n0 = nbi << 7;
  const int srow = t >> 3;
  const int scol = (((t & 7) ^ (srow & 7)) << 3);   // pre-swizzled source slot
  const int rsw  = l15 & 7;                         // read-side swizzle key

  f32x4 acc[4][4];
#pragma unroll
  for (int i = 0; i < 4; ++i)
#pragma unroll
    for (int j = 0; j < 4; ++j) acc[i][j] = f32x4{0.f, 0.f, 0.f, 0.f};

  // prologue: A(k0=0) into regs
  float4 ax[4], ay[4];
#pragma unroll
  for (int i = 0; i < 4; ++i) {
    const float* src = Af + (size_t)(m0 + 32 * i + srow) * K + scol;
    ax[i] = *(const float4*)src;
    ay[i] = *(const float4*)(src + 4);
  }

  for (int k0 = 0; k0 < K; k0 += 64) {
    __builtin_amdgcn_sched_barrier(0);
    __builtin_amdgcn_s_barrier();      // prev-iter LDS reads done (data-dep drained)
    __builtin_amdgcn_sched_barrier(0);
    // B stage (4 gload_lds, linear dest, pre-swizzled source)
#pragma unroll
    for (int i = 0; i < 4; ++i)
      gload_lds16(W + (size_t)(n0 + i * 32 + srow) * K + k0 + scol,
                  Bs + i * 2048 + t * 8);
    // A cvt (regs loaded last iter) -> linear ds_write
#pragma unroll
    for (int i = 0; i < 4; ++i) {
      u32x4 r;
      r.x = cvtpk(ax[i].x, ax[i].y); r.y = cvtpk(ax[i].z, ax[i].w);
      r.z = cvtpk(ay[i].x, ay[i].y); r.w = cvtpk(ay[i].z, ay[i].w);
      *(u32x4*)(As + (32 * i + srow) * 64 + ((t & 7) << 3)) = r;
    }
    __builtin_amdgcn_sched_barrier(0);
    // A prefetch next K-step (wrap keeps 8 loads every iter -> vmcnt invariant)
    const int kn = (k0 + 64) & (K - 1);
#pragma unroll
    for (int i = 0; i < 4; ++i) {
      const float* src = Af + (size_t)(m0 + 32 * i + srow) * K + kn + scol;
      ax[i] = *(const float4*)src;
      ay[i] = *(const float4*)(src + 4);
    }
    __builtin_amdgcn_sched_barrier(0);
    asm volatile("s_waitcnt vmcnt(8) lgkmcnt(0)" ::: "memory");  // B+dsW done; A flies
    __builtin_amdgcn_s_barrier();
    __builtin_amdgcn_sched_barrier(0);
#pragma unroll
    for (int kk = 0; kk < 2; ++kk) {
      short8 a[4], b[4];
#pragma unroll
      for (int mi = 0; mi < 4; ++mi)
        a[mi] = *(const short8*)(As + (wm * 64 + mi * 16 + l15) * 64
                                 + (((kk * 4 + g) ^ rsw) << 3));
#pragma unroll
      for (int ni = 0; ni < 4; ++ni)
        b[ni] = *(const short8*)(Bs + (wn * 64 + ni * 16 + l15) * 64
                                 + (((kk * 4 + g) ^ rsw) << 3));
#pragma unroll
      for (int mi = 0; mi < 4; ++mi)
#pragma unroll
        for (int ni = 0; ni < 4; ++ni)
          acc[mi][ni] = __builtin_amdgcn_mfma_f32_16x16x32_bf16(a[mi], b[ni], acc[mi][ni], 0, 0, 0);
    }
  }
  asm volatile("s_waitcnt vmcnt(0)" ::: "memory");   // drain dead last prefetch

#pragma unroll
  for (int ni = 0; ni < 4; ++ni) {
    const int col = n0 + wn * 64 + ni * 16 + l15;
    const float bz = bias[col];
#pragma unroll
    for (int mi = 0; mi < 4; ++mi) {
#pragma unroll
      for (int r = 0; r < 4; ++r) {
        const int row = m0 + wm * 64 + mi * 16 + g * 4 + r;
        const u16 val = f2bf((acc[mi][ni][r] + bz) * scale);
        const size_t base = ((size_t)(row >> 10) * 8 + (col >> 6)) * 65536;
        const int s = row & 1023, d = col & 63;
        if (sel == 0) {
          qhb[base + (size_t)s * 64 + d] = val;
        } else if (sel == 1) {
          khb[base + (s >> 5) * 2048 + (d >> 3) * 256 + (s & 31) * 8 + (d & 7)] = val;
        } else {
          vTb[base + (s >> 3) * 512 + d * 8 + (s & 7)] = val;
        }
      }
    }
  }
}

// ---------- final GEMM: out = attnc @ Wo^T + bo (f32 out), swizzled LDS ----
__global__ __launch_bounds__(256) void gemm_out(const u16* __restrict__ A,
                                                const u16* __restrict__ W,
                                                const float* __restrict__ bias,
                                                float* __restrict__ outp) {
  const int K = 512, N = 512;
  __shared__ __align__(16) u16 As[128 * 64];
  __shared__ __align__(16) u16 Bs[128 * 64];
  const int t    = threadIdx.x;
  const int lane = t & 63;
  const int wid  = t >> 6;
  const int g    = lane >> 4, l15 = lane & 15;
  const int wm   = wid >> 1, wn = wid & 1;
  const int wrk  = (blockIdx.x & 7) * 64 + (blockIdx.x >> 3);  // XCD-chunked
  const int mb   = wrk >> 2, nbi = wrk & 3;
  const int m0   = mb << 7, n0 = nbi << 7;
  const int srow = t >> 3;
  const int scol = (((t & 7) ^ (srow & 7)) << 3);
  const int rsw  = l15 & 7;

  f32x4 acc[4][4];
#pragma unroll
  for (int i = 0; i < 4; ++i)
#pragma unroll
    for (int j = 0; j < 4; ++j) acc[i][j] = f32x4{0.f, 0.f, 0.f, 0.f};

  for (int k0 = 0; k0 < K; k0 += 64) {
    __builtin_amdgcn_sched_barrier(0);
    __builtin_amdgcn_s_barrier();
    __builtin_amdgcn_sched_barrier(0);
#pragma unroll
    for (int i = 0; i < 4; ++i) {
      gload_lds16(A + (size_t)(m0 + i * 32 + srow) * K + k0 + scol, As + i * 2048 + t * 8);
      gload_lds16(W + (size_t)(n0 + i * 32 + srow) * K + k0 + scol, Bs + i * 2048 + t * 8);
    }
    __builtin_amdgcn_sched_barrier(0);
    asm volatile("s_waitcnt vmcnt(0)" ::: "memory");
    __builtin_amdgcn_s_barrier();
    __builtin_amdgcn_sched_barrier(0);
#pragma unroll
    for (int kk = 0; kk < 2; ++kk) {
      short8 a[4], b[4];
#pragma unroll
      for (int mi = 0; mi < 4; ++mi)
        a[mi] = *(const short8*)(As + (wm * 64 + mi * 16 + l15) * 64
                                 + (((kk * 4 + g) ^ rsw) << 3));
#pragma unroll
      for (int ni = 0; ni < 4; ++ni)
        b[ni] = *(const short8*)(Bs + (wn * 64 + ni * 16 + l15) * 64
                                 + (((kk * 4 + g) ^ rsw) << 3));
#pragma unroll
      for (int mi = 0; mi < 4; ++mi)
#pragma unroll
        for (int ni = 0; ni < 4; ++ni)
          acc[mi][ni] = __builtin_amdgcn_mfma_f32_16x16x32_bf16(a[mi], b[ni], acc[mi][ni], 0, 0, 0);
    }
  }

#pragma unroll
  for (int ni = 0; ni < 4; ++ni) {
    const int col = n0 + wn * 64 + ni * 16 + l15;
    const float bz = bias[col];
#pragma unroll
    for (int mi = 0; mi < 4; ++mi)
#pragma unroll
      for (int r = 0; r < 4; ++r) {
        const int row = m0 + wm * 64 + mi * 16 + g * 4 + r;
        outp[(size_t)row * N + col] = acc[mi][ni][r] + bz;
      }
  }
}

// ---------- flash attention: wave-pair kv-split, swapped-QK 32x32 ----------
// (unchanged from round 5)
__global__ __launch_bounds__(256, 4) void attn_kernel(const u16* __restrict__ qh,
                                                      const u16* __restrict__ kh,
                                                      const u16* __restrict__ vT,
                                                      const u64* __restrict__ maskw,
                                                      u16* __restrict__ outc) {
  const int h  = blockIdx.x;
  const int qp = blockIdx.y;
  const int b  = blockIdx.z;
  const int lane = threadIdx.x & 63;
  const int wid  = threadIdx.x >> 6;
  const int pair = wid >> 1, p = wid & 1;
  const int l31 = lane & 31;
  const int hh  = lane >> 5;
  const int hh8 = hh << 3, fourh = hh << 2, eighth = hh << 3;
  const int jt = pair ? (31 - qp) : qp;   // q-tile index 0..31
  const int q0 = jt << 5;
  const int qi = q0 + l31;
  const size_t bh = (size_t)b * 8 + h;
  const u16* Q  = qh + bh * 65536;
  const u16* Kp = kh + bh * 65536;
  const u16* Vt = vT + bh * 65536;
  const u64* mrow = maskw + (size_t)b * 32768 + qi;

  __shared__ float mO[2][32][64];
  __shared__ float mL[2][64];
  __shared__ __align__(16) float Sl[2][32];

  short8 qB[4];
#pragma unroll
  for (int i = 0; i < 4; ++i)
    qB[i] = *(const short8*)(Q + (size_t)qi * 64 + i * 16 + eighth);

  f32x16 O0, O1;
#pragma unroll
  for (int i = 0; i < 16; ++i) { O0[i] = 0.f; O1[i] = 0.f; }
  float lr[4] = {0.f, 0.f, 0.f, 0.f};

  const int nt = jt + 1;

  short8 kA[4];
#pragma unroll
  for (int i = 0; i < 4; ++i)
    kA[i] = *(const short8*)(Kp + p * 2048 + ((2 * i + hh) * 32 + l31) * 8);
  u64 wm = mrow[(size_t)p << 10];

  for (int t = p; t < nt; t += 2) {
    const int k0 = t << 5;

    f32x16 S;
#pragma unroll
    for (int i = 0; i < 16; ++i) S[i] = 0.f;
#pragma unroll
    for (int i = 0; i < 4; ++i)
      S = __builtin_amdgcn_mfma_f32_32x32x16_bf16(kA[i], qB[i], S, 0, 0, 0);

    u64 wmn = 0;
    if (t + 2 < nt) {
#pragma unroll
      for (int i = 0; i < 4; ++i)
        kA[i] = *(const short8*)(Kp + (t + 2) * 2048 + ((2 * i + hh) * 32 + l31) * 8);
      wmn = mrow[(size_t)(t + 2) << 10];
    }

    short8 vB[2][2];
#pragma unroll
    for (int t4 = 0; t4 < 2; ++t4)
#pragma unroll
      for (int j = 0; j < 2; ++j)
        vB[t4][j] = *(const short8*)(Vt + (size_t)(t * 4 + t4 * 2 + hh) * 512 + (32 * j + l31) * 8);

    const u32 wsh0 = ((u32)wm) >> hh8;
    const u32 wsh1 = ((u32)(wm >> 32)) >> hh8;
    u32 pk[8];
#pragma unroll
    for (int s = 0; s < 4; ++s) {
      const u32 wsel = (s < 2) ? wsh0 : wsh1;
      float pv[4];
#pragma unroll
      for (int r = 0; r < 4; ++r) {
        const int m = 4 * s + r;
        const u32 m2 = (wsel >> (2 * r + 16 * (s & 1))) & 3u;
        float e;
        asm("v_exp_f32 %0, %1" : "=v"(e) : "v"(S[m]));
        const float pp = (m2 != 0u) ? e : 0.f;
        lr[r] += pp;
        asm("v_ldexp_f32 %0, %1, %2" : "=v"(pv[r]) : "v"(pp), "v"(m2));
      }
      pk[2 * s]     = cvtpk(pv[0], pv[1]);
      pk[2 * s + 1] = cvtpk(pv[2], pv[3]);
    }
    wm = wmn;

#pragma unroll
    for (int t4 = 0; t4 < 2; ++t4) {
      u32 a0 = pk[4 * t4 + 0], b0 = pk[4 * t4 + 2];
      u32 a1 = pk[4 * t4 + 1], b1 = pk[4 * t4 + 3];
      asm("v_permlane32_swap_b32 %0, %1" : "+v"(a0), "+v"(b0));
      asm("v_permlane32_swap_b32 %0, %1" : "+v"(a1), "+v"(b1));
      u32x4 w; w.x = a0; w.y = a1; w.z = b0; w.w = b1;
      const short8 pa = __builtin_bit_cast(short8, w);
      O0 = __builtin_amdgcn_mfma_f32_32x32x16_bf16(pa, vB[t4][0], O0, 0, 0, 0);
      O1 = __builtin_amdgcn_mfma_f32_32x32x16_bf16(pa, vB[t4][1], O1, 0, 0, 0);
    }
  }

  float lrun = (lr[0] + lr[1]) + (lr[2] + lr[3]);

  if (p == 1) {
#pragma unroll
    for (int r = 0; r < 16; ++r) {
      mO[pair][r][lane]      = O0[r];
      mO[pair][16 + r][lane] = O1[r];
    }
    mL[pair][lane] = lrun;
  }
  __syncthreads();
  if (p == 0) {
#pragma unroll
    for (int r = 0; r < 16; ++r) {
      O0[r] += mO[pair][r][lane];
      O1[r] += mO[pair][16 + r][lane];
    }
    lrun += mL[pair][lane];

    const float ssum = lrun + __shfl_xor(lrun, 32);
    if (lane < 32) Sl[pair][l31] = (ssum > 0.f) ? 0.25f / ssum : 0.f;
    __builtin_amdgcn_sched_barrier(0);
    asm volatile("s_waitcnt lgkmcnt(0)" ::: "memory");
    __builtin_amdgcn_sched_barrier(0);
#pragma unroll
    for (int t2 = 0; t2 < 4; ++t2) {
      const float4 inv4 = *(const float4*)&Sl[pair][8 * t2 + fourh];
#pragma unroll
      for (int r = 0; r < 4; ++r) {
        const int m = 4 * t2 + r;
        const float iv = (r == 0) ? inv4.x : (r == 1) ? inv4.y : (r == 2) ? inv4.z : inv4.w;
        const int qrow = q0 + 8 * t2 + fourh + r;
        u16* op = outc + ((size_t)b * 1024 + qrow) * 512 + h * 64;
        op[l31]      = f2bf(O0[m] * iv);
        op[32 + l31] = f2bf(O1[m] * iv);
      }
    }
  }
}

// ---------- launch ----------
extern "C" void kernel_launch(void* const* d_in, const int* in_sizes, int n_in,
                              void* d_out, int out_size, void* d_ws, size_t ws_size,
                              hipStream_t stream) {
  (void)in_sizes; (void)n_in; (void)out_size; (void)ws_size;
  const float* q    = (const float*)d_in[0];
  const float* k    = (const float*)d_in[1];
  const float* v    = (const float*)d_in[2];
  const int*  q_seq = (const int*)d_in[3];
  const int*  c_seq = (const int*)d_in[4];
  const float* Wq   = (const float*)d_in[5];
  const float* bq   = (const float*)d_in[6];
  const float* Wk   = (const float*)d_in[7];
  const float* bk   = (const float*)d_in[8];
  const float* Wv   = (const float*)d_in[9];
  const float* bv   = (const float*)d_in[10];
  const float* Wo   = (const float*)d_in[11];
  const float* bo   = (const float*)d_in[12];
  float* out = (float*)d_out;

  char* ws = (char*)d_ws;
  const size_t SZH = 16ull * 8 * 1024 * 64 * 2;   // 16.78 MB per [B][H][...] bf16
  u16* qhb   = (u16*)(ws + 0 * SZH);
  u16* khb   = (u16*)(ws + 1 * SZH);
  u16* vTb   = (u16*)(ws + 2 * SZH);
  u16* attnc = (u16*)(ws + 3 * SZH);
  u16* Wvb = (u16*)(ws + 4 * SZH + 0 * 524288);
  u16* Wkb = (u16*)(ws + 4 * SZH + 1 * 524288);
  u16* Wqb = (u16*)(ws + 4 * SZH + 2 * 524288);
  u16* Wob = (u16*)(ws + 4 * SZH + 3 * 524288);
  int2* meta  = (int2*)(ws + 4 * SZH + 4 * 524288);
  u64* maskw  = (u64*)(ws + 4 * SZH + 4 * 524288 + 131072);

  const int n8w = 512 * 512 / 8;
  cast4_kernel<<<dim3(n8w / 256, 4), 256, 0, stream>>>(Wv, Wk, Wq, Wo,
                                                       Wvb, Wkb, Wqb, Wob, n8w);
  pack_kernel<<<64, 256, 0, stream>>>(q_seq, c_seq, meta, 16384);
  mask_kernel<<<dim3(4, 32, 16), 256, 0, stream>>>(meta, maskw);

  const float KSCALE = 0.18033688011112042f;   // log2(e)/8 -> softmax exp is 2^s
  gemm_qkv<<<dim3(512, 3), 256, 0, stream>>>(q, k, v, Wvb, Wkb, Wqb,
                                             bv, bk, bq, qhb, khb, vTb, KSCALE);
  attn_kernel<<<dim3(8, 16, 16), 256, 0, stream>>>(qhb, khb, vTb, maskw, attnc);
  gemm_out<<<512, 256, 0, stream>>>(attnc, Wob, bo, out);
}